// Round 11
// baseline (624.850 us; speedup 1.0000x reference)
//
#include <hip/hip_runtime.h>
#include <math.h>

#define Bb 8
#define Nn 1024
#define Kk 32
#define Dd 256
#define Hh 8
#define DHh 32
#define TDIMt 16
#define NBnb 32
#define HIDh 128
#define NSns 128
#define SHDs 9
#define EINe 304   // NB + TDIM + 2*NS
#define NCOLS 1536 // vproj 256 | hsrc 128 | hdst 128 | qw 1024

typedef __bf16 bf16_t;
typedef bf16_t bf16x8 __attribute__((ext_vector_type(8)));
typedef bf16_t bf16x4 __attribute__((ext_vector_type(4)));
typedef float floatx4 __attribute__((ext_vector_type(4)));

__device__ __forceinline__ float gelu_fast(float x){
  float g = 1.5957691216057308f*(x + 0.044715f*x*x*x);
  return x*__builtin_amdgcn_rcpf(1.0f + __expf(-g));
}
__device__ __forceinline__ float tanh_fast(float x){
  return 1.0f - 2.0f*__builtin_amdgcn_rcpf(1.0f + __expf(2.0f*x));
}

// ---------------- kNN: 256-thread blocks, one wave per node (4 nodes/block) ----------------
__global__ __launch_bounds__(256) void knn_kernel(const float* __restrict__ x, int* __restrict__ src){
  int wave = threadIdx.x >> 6;
  int lane = threadIdx.x & 63;
  int bn = blockIdx.x*4 + wave;
  int b = bn >> 10;
  int n = bn & (Nn-1);
  const float* xb = x + (size_t)b*Nn*3;
  float px = xb[n*3+0], py = xb[n*3+1], pz = xb[n*3+2];
  float d2v[16];
  #pragma unroll
  for (int i=0;i<16;i++){
    int j = i*64 + lane;
    float dx = px - xb[j*3+0];
    float dy = py - xb[j*3+1];
    float dz = pz - xb[j*3+2];
    d2v[i] = dx*dx + dy*dy + dz*dz;
  }
  for (int s=0;s<Kk;s++){
    float best = 3.0e38f; int bslot = 0;
    #pragma unroll
    for (int i=0;i<16;i++){
      if (d2v[i] < best){ best = d2v[i]; bslot = i; }
    }
    int bj = bslot*64 + lane;
    #pragma unroll
    for (int off=32; off>=1; off>>=1){
      float ov = __shfl_xor(best, off);
      int   oj = __shfl_xor(bj,   off);
      if (ov < best || (ov == best && oj < bj)){ best = ov; bj = oj; }
    }
    if ((bj & 63) == lane){
      int sl = bj >> 6;
      #pragma unroll
      for (int i=0;i<16;i++) if (i==sl) d2v[i] = 3.0e38f;
    }
    if (lane == 0) src[(size_t)bn*Kk + s] = bj;
  }
}

// ---------------- embed ----------------
__global__ __launch_bounds__(256) void embed_kernel(const float* __restrict__ y, const float* __restrict__ t,
    const float* __restrict__ We, float* __restrict__ node, bf16_t* __restrict__ node_bf){
  int bn = blockIdx.x; int b = bn >> 10;
  int c = threadIdx.x;
  float f0 = y[(size_t)bn*3+0], f1 = y[(size_t)bn*3+1], f2 = y[(size_t)bn*3+2];
  float a = f0*We[0*Dd+c] + f1*We[1*Dd+c] + f2*We[2*Dd+c];
  #pragma unroll
  for (int i=0;i<TDIMt;i++) a += t[b*TDIMt+i]*We[(3+i)*Dd+c];
  node[(size_t)bn*Dd + c] = a;
  node_bf[(size_t)bn*Dd + c] = (bf16_t)a;
}

// ---------------- weight prep: Wt[l][col][k] bf16, cols 0..511 ----------------
__global__ __launch_bounds__(256) void wprep_kernel(const float* __restrict__ Wv,
    const float* __restrict__ Wk1, bf16_t* __restrict__ Wt){
  int l = blockIdx.x, c = blockIdx.y, k = threadIdx.x;
  const float* wk1l = Wk1 + (size_t)l*EINe*HIDh;
  float v;
  if (c < 256)       v = Wv[(size_t)l*265*Dd + (size_t)k*Dd + c];
  else if (c < 384){ int c2 = c-256; v = (k < 128) ? wk1l[(48+k)*HIDh + c2] : 0.0f; }
  else             { int c2 = c-384; v = (k < 128) ? wk1l[(176+k)*HIDh + c2] : 0.0f; }
  Wt[((size_t)l*NCOLS + c)*Dd + k] = (bf16_t)v;
}

// ---------------- weight prep: fused qw weights M[i][h*128+c] -> cols 512..1535 ----------------
__global__ __launch_bounds__(256) void wprepM_kernel(const float* __restrict__ Wq,
    const float* __restrict__ Wk2, bf16_t* __restrict__ Wt){
  int l = blockIdx.x, y = blockIdx.y, i = threadIdx.x;
  int h = y >> 7, c = y & 127;
  const float* wq  = Wq  + (size_t)l*Dd*Dd   + (size_t)i*Dd + h*DHh;
  const float* wk2 = Wk2 + (size_t)l*HIDh*Dd + (size_t)c*Dd + h*DHh;
  float a = 0.0f;
  #pragma unroll
  for (int d=0; d<DHh; d++) a += wq[d]*wk2[d];
  Wt[((size_t)l*NCOLS + 512 + y)*Dd + i] = (bf16_t)a;
}

// ---------------- weight prep: Wo transposed bf16 ----------------
__global__ __launch_bounds__(256) void wprepO_kernel(const float* __restrict__ Wo, bf16_t* __restrict__ Wto){
  int l = blockIdx.x, c = blockIdx.y, k = threadIdx.x;
  Wto[((size_t)l*Dd + c)*Dd + k] = (bf16_t)Wo[(size_t)l*Dd*Dd + (size_t)k*Dd + c];
}

// ---------------- weight prep: WrbfT[l][c][k] bf16 ----------------
__global__ __launch_bounds__(32) void wprepR_kernel(const float* __restrict__ Wk1, bf16_t* __restrict__ WrbfT){
  int l = blockIdx.x, c = blockIdx.y, k = threadIdx.x;   // k < 32
  WrbfT[((size_t)l*HIDh + c)*NBnb + k] = (bf16_t)Wk1[(size_t)l*EINe*HIDh + (size_t)k*HIDh + c];
}

// ---------------- t_hd[l][b][c] = bk1 + t@Wk1_t ----------------
__global__ __launch_bounds__(128) void tprep_kernel(const float* __restrict__ t,
    const float* __restrict__ Wk1, const float* __restrict__ bk1, float* __restrict__ t_hd){
  int l = blockIdx.x, b = blockIdx.y, c = threadIdx.x;
  const float* wk1l = Wk1 + (size_t)l*EINe*HIDh;
  float a = bk1[l*HIDh + c];
  #pragma unroll
  for (int i=0;i<TDIMt;i++) a += t[b*TDIMt+i]*wk1l[(32+i)*HIDh + c];
  t_hd[(l*Bb + b)*HIDh + c] = a;
}

// ---------------- proj GEMM ----------------
// by 0..3 -> vproj_bf (bf16), 4..5 -> hsrc_bf (bf16), 6..7 -> hdst_f (f32), 8..23 -> qw_bf (bf16)
__global__ __launch_bounds__(256) void gemm_proj(const bf16_t* __restrict__ A,
    const bf16_t* __restrict__ Wt_all, bf16_t* __restrict__ vproj_bf,
    bf16_t* __restrict__ hsrc_bf, float* __restrict__ hdst_f,
    bf16_t* __restrict__ qw_bf, int layer){
  const int tid = threadIdx.x;
  const int wave = tid>>6, lane = tid&63;
  const int row16 = lane&15, quad = lane>>4;
  const int m_base = blockIdx.x*128 + wave*32;
  const int n_base = blockIdx.y*64;
  const bf16_t* Bw = Wt_all + (size_t)layer*NCOLS*Dd;

  floatx4 acc[2][4];
  #pragma unroll
  for (int mi=0;mi<2;mi++)
    #pragma unroll
    for (int ni=0;ni<4;ni++){ floatx4 z = {0.f,0.f,0.f,0.f}; acc[mi][ni] = z; }

  const bf16_t* a0p = A  + (size_t)(m_base + row16)*Dd + quad*8;
  const bf16_t* bp  = Bw + (size_t)(n_base + row16)*Dd + quad*8;
  #pragma unroll
  for (int ks=0; ks<8; ks++){
    bf16x8 a0 = *(const bf16x8*)(a0p + ks*32);
    bf16x8 a1 = *(const bf16x8*)(a0p + 16*Dd + ks*32);
    #pragma unroll
    for (int ni=0;ni<4;ni++){
      bf16x8 b = *(const bf16x8*)(bp + (size_t)ni*16*Dd + ks*32);
      acc[0][ni] = __builtin_amdgcn_mfma_f32_16x16x32_bf16(a0, b, acc[0][ni], 0,0,0);
      acc[1][ni] = __builtin_amdgcn_mfma_f32_16x16x32_bf16(a1, b, acc[1][ni], 0,0,0);
    }
  }

  const int by = blockIdx.y;
  #pragma unroll
  for (int mi=0;mi<2;mi++)
    #pragma unroll
    for (int ni=0;ni<4;ni++){
      int col = n_base + ni*16 + row16;
      #pragma unroll
      for (int r=0;r<4;r++){
        int row = m_base + mi*16 + quad*4 + r;
        float v = acc[mi][ni][r];
        if (by < 4)       vproj_bf[(size_t)row*256 + col]       = (bf16_t)v;
        else if (by < 6)  hsrc_bf[(size_t)row*128 + (col-256)]  = (bf16_t)v;
        else if (by < 8)  hdst_f[(size_t)row*128 + (col-384)]   = v;
        else              qw_bf[(size_t)row*1024 + (col-512)]   = (bf16_t)v;
      }
    }
}

// ---------------- upd GEMM: node = act(node + agg_bf @ Wo) ----------------
__global__ __launch_bounds__(256) void gemm_upd(const bf16_t* __restrict__ A,
    const bf16_t* __restrict__ Wto, float* __restrict__ node, bf16_t* __restrict__ node_bf, int layer){
  const int tid = threadIdx.x;
  const int wave = tid>>6, lane = tid&63;
  const int row16 = lane&15, quad = lane>>4;
  const int m_base = blockIdx.x*128 + wave*32;
  const int n_base = blockIdx.y*64;
  const bf16_t* Bw = Wto + (size_t)layer*Dd*Dd;

  floatx4 acc[2][4];
  #pragma unroll
  for (int mi=0;mi<2;mi++)
    #pragma unroll
    for (int ni=0;ni<4;ni++){ floatx4 z = {0.f,0.f,0.f,0.f}; acc[mi][ni] = z; }

  const bf16_t* a0p = A  + (size_t)(m_base + row16)*Dd + quad*8;
  const bf16_t* bp  = Bw + (size_t)(n_base + row16)*Dd + quad*8;
  #pragma unroll
  for (int ks=0; ks<8; ks++){
    bf16x8 a0 = *(const bf16x8*)(a0p + ks*32);
    bf16x8 a1 = *(const bf16x8*)(a0p + 16*Dd + ks*32);
    #pragma unroll
    for (int ni=0;ni<4;ni++){
      bf16x8 b = *(const bf16x8*)(bp + (size_t)ni*16*Dd + ks*32);
      acc[0][ni] = __builtin_amdgcn_mfma_f32_16x16x32_bf16(a0, b, acc[0][ni], 0,0,0);
      acc[1][ni] = __builtin_amdgcn_mfma_f32_16x16x32_bf16(a1, b, acc[1][ni], 0,0,0);
    }
  }

  #pragma unroll
  for (int mi=0;mi<2;mi++)
    #pragma unroll
    for (int ni=0;ni<4;ni++){
      int col = n_base + ni*16 + row16;
      #pragma unroll
      for (int r=0;r<4;r++){
        int row = m_base + mi*16 + quad*4 + r;
        float v = acc[mi][ni][r] + node[(size_t)row*Dd + col];
        if (col < 64)       v = gelu_fast(v);
        else if (col < 128) v = tanh_fast(v);
        node[(size_t)row*Dd + col] = v;
        node_bf[(size_t)row*Dd + col] = (bf16_t)v;
      }
    }
}

// ---------------- attn: TWO nodes per block ----------------
__global__ __launch_bounds__(256) void attn_kernel(
    const float* __restrict__ x, const int* __restrict__ src,
    const bf16_t* __restrict__ vproj_bf, const bf16_t* __restrict__ hsrc_bf,
    const float* __restrict__ hdst_f, const bf16_t* __restrict__ qw_bf,
    const float* __restrict__ t_hd, const bf16_t* __restrict__ WrbfT,
    const float* __restrict__ Wvg, const float* __restrict__ Woo,
    bf16_t* __restrict__ agg_bf, float* __restrict__ out, int layer){

  // per-node LDS regions (u = 0,1):
  __shared__ __align__(16) char smem[27360];
  #define S_RBF(u)   ((bf16_t*)(smem + (u)*2048))
  #define S_H(u)     ((bf16_t*)(smem + 4096  + (u)*8704))   // [32][136]
  #define S_SHm(u)   ((float*)(smem + 21504 + (u)*1280))    // [32][10]
  #define S_CUT(u)   ((float*)(smem + 24064 + (u)*128))
  #define S_SRCV(u)  ((int*)  (smem + 24320 + (u)*128))
  #define S_LOGIT(u) ((float*)(smem + 24576 + (u)*1024))    // [32][8]
  #define S_POOL(u)  ((float*)(smem + 26624 + (u)*320))     // [8][10]
  #define S_RED(u)   ((float*)(smem + 27264 + (u)*48))      // [4][3]

  const int tid = threadIdx.x;
  const int bn0 = blockIdx.x*2;
  const int b   = bn0 >> 10;   // bn0 even => both nodes in same batch
  const int wave = tid>>6, lane = tid&63;
  const int row16 = lane&15, quad = lane>>4;

  // P0: geometry for both nodes; thread = (k = tid>>3, i = tid&7)
  #pragma unroll
  for (int u=0;u<2;u++){
    const int bn = bn0 + u;
    int k = tid>>3, i = tid&7;
    int j = src[(size_t)bn*Kk + k];
    if (i == 0) S_SRCV(u)[k] = j;
    float ax = x[(size_t)bn*3+0], ay = x[(size_t)bn*3+1], az = x[(size_t)bn*3+2];
    const float* xj = x + ((size_t)b*Nn + j)*3;
    float dx = ax - xj[0], dy = ay - xj[1], dz = az - xj[2];
    float rr = sqrtf(dx*dx + dy*dy + dz*dz);
    float xx = 10.0f*(1.0f - rr*0.5f);
    float cu = (xx > 0.0f) ? 1.4f*__expf(-__builtin_amdgcn_rcpf(xx)) : 0.0f;
    if (i == 0) S_CUT(u)[k] = cu;
    if (i == 1){
      float inv = __builtin_amdgcn_rcpf(fmaxf(rr, 1e-9f));
      float ux = dx*inv, uy = dy*inv, uz = dz*inv;
      float* sh = S_SHm(u) + k*10;
      sh[0] = 1.0f;
      sh[1] = 1.7320508075688772f*ux;
      sh[2] = 1.7320508075688772f*uy;
      sh[3] = 1.7320508075688772f*uz;
      sh[4] = 3.872983346207417f*ux*uy;
      sh[5] = 3.872983346207417f*uy*uz;
      sh[6] = 1.118033988749895f*(3.0f*uz*uz - 1.0f);
      sh[7] = 3.872983346207417f*ux*uz;
      sh[8] = 1.9364916731037085f*(ux*ux - uy*uy);
    }
    float rs = rr*15.5f;
    float base = (float)(i*4);
    bf16x4 pv;
    #pragma unroll
    for (int c=0;c<4;c++){
      float dd = rs - (base + (float)c);
      pv[c] = (bf16_t)(__expf(-dd*dd)*4.798224586623f*cu);
    }
    *(bf16x4*)(S_RBF(u) + (i>>1)*256 + k*8 + (i&1)*4) = pv;
  }
  __syncthreads();   // B1

  // P1: hs staging loads (both nodes) + h-MFMA (both nodes; B-frags shared)
  int hrow[2], hc8[2];
  #pragma unroll
  for (int rep=0;rep<2;rep++){
    int q = tid + rep*256;
    hrow[rep] = q>>4; hc8[rep] = q&15;
  }
  bf16x8 hsv[2][2];
  #pragma unroll
  for (int u=0;u<2;u++)
    #pragma unroll
    for (int rep=0;rep<2;rep++)
      hsv[u][rep] = *(const bf16x8*)(hsrc_bf + ((size_t)b*Nn + S_SRCV(u)[hrow[rep]])*128 + hc8[rep]*8);

  floatx4 acc[2][2][2];
  {
    const bf16_t* bp = WrbfT + ((size_t)layer*HIDh + wave*32 + row16)*NBnb + quad*8;
    bf16x8 b0 = *(const bf16x8*)(bp);
    bf16x8 b1 = *(const bf16x8*)(bp + 16*NBnb);
    #pragma unroll
    for (int u=0;u<2;u++){
      bf16x8 a0 = *(const bf16x8*)(S_RBF(u) + quad*256 + row16*8);
      bf16x8 a1 = *(const bf16x8*)(S_RBF(u) + quad*256 + (16+row16)*8);
      #pragma unroll
      for (int mi=0;mi<2;mi++)
        #pragma unroll
        for (int ni=0;ni<2;ni++){ floatx4 z = {0.f,0.f,0.f,0.f}; acc[u][mi][ni] = z; }
      acc[u][0][0] = __builtin_amdgcn_mfma_f32_16x16x32_bf16(a0, b0, acc[u][0][0], 0,0,0);
      acc[u][0][1] = __builtin_amdgcn_mfma_f32_16x16x32_bf16(a0, b1, acc[u][0][1], 0,0,0);
      acc[u][1][0] = __builtin_amdgcn_mfma_f32_16x16x32_bf16(a1, b0, acc[u][1][0], 0,0,0);
      acc[u][1][1] = __builtin_amdgcn_mfma_f32_16x16x32_bf16(a1, b1, acc[u][1][1], 0,0,0);
    }
  }
  #pragma unroll
  for (int u=0;u<2;u++)
    #pragma unroll
    for (int rep=0;rep<2;rep++)
      *(bf16x8*)(S_H(u) + hrow[rep]*136 + hc8[rep]*8) = hsv[u][rep];
  __syncthreads();   // B2

  // P2: epilogue — h = gelu(acc + hd + hs), in place, both nodes
  #pragma unroll
  for (int u=0;u<2;u++){
    const int bn = bn0 + u;
    #pragma unroll
    for (int ni=0;ni<2;ni++){
      int c = wave*32 + ni*16 + row16;
      float hdv = hdst_f[(size_t)bn*128 + c] + t_hd[(size_t)(layer*Bb + b)*HIDh + c];
      #pragma unroll
      for (int mi=0;mi<2;mi++){
        #pragma unroll
        for (int r=0;r<4;r++){
          int e = mi*16 + quad*4 + r;
          float hs = (float)S_H(u)[e*136 + c];
          S_H(u)[e*136 + c] = (bf16_t)gelu_fast(acc[u][mi][ni][r] + hdv + hs);
        }
      }
    }
  }
  __syncthreads();   // B3

  // P3: logits MFMA — all 4 waves: u = wave>>1, half = wave&1
  {
    const int u = wave>>1, w2 = wave&1;
    floatx4 la = {0.f,0.f,0.f,0.f};
    const bf16_t* qp = qw_bf + (size_t)(bn0+u)*1024 + row16*HIDh + quad*8;
    #pragma unroll
    for (int ks=0; ks<4; ks++){
      bf16x8 a = *(const bf16x8*)(S_H(u) + (w2*16 + row16)*136 + ks*32 + quad*8);
      bf16x8 bq = *(const bf16x8*)(qp + ks*32);
      la = __builtin_amdgcn_mfma_f32_16x16x32_bf16(a, bq, la, 0,0,0);
    }
    if (row16 < Hh){
      #pragma unroll
      for (int r=0;r<4;r++)
        S_LOGIT(u)[(w2*16 + quad*4 + r)*8 + row16] = la[r]*0.17677669529663687f;
    }
  }
  __syncthreads();   // B4

  // P4: softmax + pooling + SH pooling + store / fused out, both nodes
  #pragma unroll
  for (int u=0;u<2;u++){
    const int bn = bn0 + u;
    const int l = tid & 63;
    const int k = l & 31;
    const int h = tid >> 5;
    float lv = S_LOGIT(u)[k*8 + h];
    float m = lv;
    #pragma unroll
    for (int off=16; off>=1; off>>=1) m = fmaxf(m, __shfl_xor(m, off));
    float w = S_CUT(u)[k]*__expf(lv - m);
    float ss = w;
    #pragma unroll
    for (int off=16; off>=1; off>>=1) ss += __shfl_xor(ss, off);
    float alpha = w*__builtin_amdgcn_rcpf(ss + 1e-9f);

    const int half = l & 32;
    const int sgi = (k < SHDs) ? k : 0;
    float a_main = 0.0f, a_sh = 0.0f;
    #pragma unroll
    for (int kk=0; kk<Kk; kk++){
      float av = __shfl(alpha, half + kk);
      a_main += av * (float)vproj_bf[((size_t)b*Nn + S_SRCV(u)[kk])*256 + tid];
      a_sh   += av * S_SHm(u)[kk*10 + sgi];
    }
    if (k < SHDs) S_POOL(u)[h*10 + k] = a_sh;

    // same-wave LDS write->read (DS ops in-order within a wave)
    const float* wvsh = Wvg + (size_t)layer*265*Dd + 256*Dd;
    #pragma unroll
    for (int sg=0; sg<SHDs; sg++) a_main += S_POOL(u)[h*10 + sg]*wvsh[sg*Dd + tid];

    if (layer < 3){
      agg_bf[(size_t)bn*Dd + tid] = (bf16_t)a_main;
    } else {
      float p0 = a_main*Woo[tid*3+0];
      float p1 = a_main*Woo[tid*3+1];
      float p2 = a_main*Woo[tid*3+2];
      #pragma unroll
      for (int off=32; off>=1; off>>=1){
        p0 += __shfl_xor(p0, off);
        p1 += __shfl_xor(p1, off);
        p2 += __shfl_xor(p2, off);
      }
      if (lane == 0){ S_RED(u)[wave*3+0]=p0; S_RED(u)[wave*3+1]=p1; S_RED(u)[wave*3+2]=p2; }
      __syncthreads();
      if (tid < 3)
        out[(size_t)bn*3 + tid] = S_RED(u)[0*3+tid]+S_RED(u)[1*3+tid]+S_RED(u)[2*3+tid]+S_RED(u)[3*3+tid];
    }
  }
}

extern "C" void kernel_launch(void* const* d_in, const int* in_sizes, int n_in,
                              void* d_out, int out_size, void* d_ws, size_t ws_size,
                              hipStream_t stream){
  const float* x   = (const float*)d_in[0];
  const float* y   = (const float*)d_in[1];
  const float* t   = (const float*)d_in[2];
  const float* We  = (const float*)d_in[3];
  const float* Wk1 = (const float*)d_in[4];
  const float* bk1 = (const float*)d_in[5];
  const float* Wk2 = (const float*)d_in[6];
  const float* Wq  = (const float*)d_in[7];
  const float* Wv  = (const float*)d_in[8];
  const float* Wo  = (const float*)d_in[9];
  const float* Woo = (const float*)d_in[10];
  float* out = (float*)d_out;

  char* ws = (char*)d_ws;
  size_t off = 0;
  auto take = [&](size_t bytes)->char*{ char* p = ws + off; off = (off + bytes + 255) & ~(size_t)255; return p; };

  int*    src      = (int*)   take((size_t)Bb*Nn*Kk*4);
  float*  node     = (float*) take((size_t)Bb*Nn*Dd*4);
  bf16_t* node_bf  = (bf16_t*)take((size_t)Bb*Nn*Dd*2);
  bf16_t* agg_bf   = (bf16_t*)take((size_t)Bb*Nn*Dd*2);
  bf16_t* vproj_bf = (bf16_t*)take((size_t)Bb*Nn*256*2);
  bf16_t* hsrc_bf  = (bf16_t*)take((size_t)Bb*Nn*128*2);
  float*  hdst_f   = (float*) take((size_t)Bb*Nn*128*4);
  bf16_t* qw_bf    = (bf16_t*)take(((size_t)Bb*Nn*1024 + 2048)*2);  // +pad for B-frag overread
  bf16_t* Wt       = (bf16_t*)take((size_t)4*NCOLS*Dd*2);
  bf16_t* Wto      = (bf16_t*)take((size_t)3*Dd*Dd*2);
  bf16_t* WrbfT    = (bf16_t*)take((size_t)4*HIDh*NBnb*2);
  float*  t_hd     = (float*) take((size_t)4*Bb*HIDh*4);

  // weight prep
  wprep_kernel <<<dim3(4,512),  256, 0, stream>>>(Wv, Wk1, Wt);
  wprepM_kernel<<<dim3(4,1024), 256, 0, stream>>>(Wq, Wk2, Wt);
  wprepO_kernel<<<dim3(3,256),  256, 0, stream>>>(Wo, Wto);
  wprepR_kernel<<<dim3(4,128),  32,  0, stream>>>(Wk1, WrbfT);
  tprep_kernel <<<dim3(4,8),    128, 0, stream>>>(t, Wk1, bk1, t_hd);

  knn_kernel  <<<dim3(Bb*Nn/4), 256, 0, stream>>>(x, src);
  embed_kernel<<<dim3(Bb*Nn), 256, 0, stream>>>(y, t, We, node, node_bf);

  for (int l=0; l<4; l++){
    gemm_proj<<<dim3(64,24), 256, 0, stream>>>(node_bf, Wt, vproj_bf, hsrc_bf, hdst_f, qw_bf, l);
    attn_kernel<<<dim3(Bb*Nn/2), 256, 0, stream>>>(x, src, vproj_bf, hsrc_bf, hdst_f, qw_bf,
                                                   t_hd, WrbfT, Wv, Woo, agg_bf, out, l);
    if (l < 3){
      gemm_upd<<<dim3(64,4), 256, 0, stream>>>(agg_bf, Wto, node, node_bf, l);
    }
  }
}

// Round 12
// 613.115 us; speedup vs baseline: 1.0191x; 1.0191x over previous
//
#include <hip/hip_runtime.h>
#include <math.h>

#define Bb 8
#define Nn 1024
#define Kk 32
#define Dd 256
#define Hh 8
#define DHh 32
#define TDIMt 16
#define NBnb 32
#define HIDh 128
#define NSns 128
#define SHDs 9
#define EINe 304   // NB + TDIM + 2*NS
#define NCOLS 1536 // vproj 256 | hsrc 128 | hdst 128 | qw 1024

typedef __bf16 bf16_t;
typedef bf16_t bf16x8 __attribute__((ext_vector_type(8)));
typedef bf16_t bf16x4 __attribute__((ext_vector_type(4)));
typedef float floatx4 __attribute__((ext_vector_type(4)));

__device__ __forceinline__ float gelu_fast(float x){
  float g = 1.5957691216057308f*(x + 0.044715f*x*x*x);
  return x*__builtin_amdgcn_rcpf(1.0f + __expf(-g));
}
__device__ __forceinline__ float tanh_fast(float x){
  return 1.0f - 2.0f*__builtin_amdgcn_rcpf(1.0f + __expf(2.0f*x));
}

// ---------------- kNN: 256-thread blocks, one wave per node (4 nodes/block) ----------------
__global__ __launch_bounds__(256) void knn_kernel(const float* __restrict__ x, int* __restrict__ src){
  int wave = threadIdx.x >> 6;
  int lane = threadIdx.x & 63;
  int bn = blockIdx.x*4 + wave;
  int b = bn >> 10;
  int n = bn & (Nn-1);
  const float* xb = x + (size_t)b*Nn*3;
  float px = xb[n*3+0], py = xb[n*3+1], pz = xb[n*3+2];
  float d2v[16];
  #pragma unroll
  for (int i=0;i<16;i++){
    int j = i*64 + lane;
    float dx = px - xb[j*3+0];
    float dy = py - xb[j*3+1];
    float dz = pz - xb[j*3+2];
    d2v[i] = dx*dx + dy*dy + dz*dz;
  }
  for (int s=0;s<Kk;s++){
    float best = 3.0e38f; int bslot = 0;
    #pragma unroll
    for (int i=0;i<16;i++){
      if (d2v[i] < best){ best = d2v[i]; bslot = i; }
    }
    int bj = bslot*64 + lane;
    #pragma unroll
    for (int off=32; off>=1; off>>=1){
      float ov = __shfl_xor(best, off);
      int   oj = __shfl_xor(bj,   off);
      if (ov < best || (ov == best && oj < bj)){ best = ov; bj = oj; }
    }
    if ((bj & 63) == lane){
      int sl = bj >> 6;
      #pragma unroll
      for (int i=0;i<16;i++) if (i==sl) d2v[i] = 3.0e38f;
    }
    if (lane == 0) src[(size_t)bn*Kk + s] = bj;
  }
}

// ---------------- embed ----------------
__global__ __launch_bounds__(256) void embed_kernel(const float* __restrict__ y, const float* __restrict__ t,
    const float* __restrict__ We, float* __restrict__ node, bf16_t* __restrict__ node_bf){
  int bn = blockIdx.x; int b = bn >> 10;
  int c = threadIdx.x;
  float f0 = y[(size_t)bn*3+0], f1 = y[(size_t)bn*3+1], f2 = y[(size_t)bn*3+2];
  float a = f0*We[0*Dd+c] + f1*We[1*Dd+c] + f2*We[2*Dd+c];
  #pragma unroll
  for (int i=0;i<TDIMt;i++) a += t[b*TDIMt+i]*We[(3+i)*Dd+c];
  node[(size_t)bn*Dd + c] = a;
  node_bf[(size_t)bn*Dd + c] = (bf16_t)a;
}

// ---------------- weight prep: Wt[l][col][k] bf16, cols 0..511 ----------------
__global__ __launch_bounds__(256) void wprep_kernel(const float* __restrict__ Wv,
    const float* __restrict__ Wk1, bf16_t* __restrict__ Wt){
  int l = blockIdx.x, c = blockIdx.y, k = threadIdx.x;
  const float* wk1l = Wk1 + (size_t)l*EINe*HIDh;
  float v;
  if (c < 256)       v = Wv[(size_t)l*265*Dd + (size_t)k*Dd + c];
  else if (c < 384){ int c2 = c-256; v = (k < 128) ? wk1l[(48+k)*HIDh + c2] : 0.0f; }
  else             { int c2 = c-384; v = (k < 128) ? wk1l[(176+k)*HIDh + c2] : 0.0f; }
  Wt[((size_t)l*NCOLS + c)*Dd + k] = (bf16_t)v;
}

// ---------------- weight prep: fused qw weights M[i][h*128+c] -> cols 512..1535 ----------------
__global__ __launch_bounds__(256) void wprepM_kernel(const float* __restrict__ Wq,
    const float* __restrict__ Wk2, bf16_t* __restrict__ Wt){
  int l = blockIdx.x, y = blockIdx.y, i = threadIdx.x;
  int h = y >> 7, c = y & 127;
  const float* wq  = Wq  + (size_t)l*Dd*Dd   + (size_t)i*Dd + h*DHh;
  const float* wk2 = Wk2 + (size_t)l*HIDh*Dd + (size_t)c*Dd + h*DHh;
  float a = 0.0f;
  #pragma unroll
  for (int d=0; d<DHh; d++) a += wq[d]*wk2[d];
  Wt[((size_t)l*NCOLS + 512 + y)*Dd + i] = (bf16_t)a;
}

// ---------------- weight prep: Wo transposed bf16 ----------------
__global__ __launch_bounds__(256) void wprepO_kernel(const float* __restrict__ Wo, bf16_t* __restrict__ Wto){
  int l = blockIdx.x, c = blockIdx.y, k = threadIdx.x;
  Wto[((size_t)l*Dd + c)*Dd + k] = (bf16_t)Wo[(size_t)l*Dd*Dd + (size_t)k*Dd + c];
}

// ---------------- weight prep: WrbfT[l][c][k] bf16 ----------------
__global__ __launch_bounds__(32) void wprepR_kernel(const float* __restrict__ Wk1, bf16_t* __restrict__ WrbfT){
  int l = blockIdx.x, c = blockIdx.y, k = threadIdx.x;   // k < 32
  WrbfT[((size_t)l*HIDh + c)*NBnb + k] = (bf16_t)Wk1[(size_t)l*EINe*HIDh + (size_t)k*HIDh + c];
}

// ---------------- t_hd[l][b][c] = bk1 + t@Wk1_t ----------------
__global__ __launch_bounds__(128) void tprep_kernel(const float* __restrict__ t,
    const float* __restrict__ Wk1, const float* __restrict__ bk1, float* __restrict__ t_hd){
  int l = blockIdx.x, b = blockIdx.y, c = threadIdx.x;
  const float* wk1l = Wk1 + (size_t)l*EINe*HIDh;
  float a = bk1[l*HIDh + c];
  #pragma unroll
  for (int i=0;i<TDIMt;i++) a += t[b*TDIMt+i]*wk1l[(32+i)*HIDh + c];
  t_hd[(l*Bb + b)*HIDh + c] = a;
}

// ---------------- proj GEMM ----------------
// by 0..3 -> vproj_bf (bf16), 4..5 -> hsrc_bf (bf16), 6..7 -> hdst_f (f32), 8..23 -> qw_bf (bf16)
__global__ __launch_bounds__(256) void gemm_proj(const bf16_t* __restrict__ A,
    const bf16_t* __restrict__ Wt_all, bf16_t* __restrict__ vproj_bf,
    bf16_t* __restrict__ hsrc_bf, float* __restrict__ hdst_f,
    bf16_t* __restrict__ qw_bf, int layer){
  const int tid = threadIdx.x;
  const int wave = tid>>6, lane = tid&63;
  const int row16 = lane&15, quad = lane>>4;
  const int m_base = blockIdx.x*128 + wave*32;
  const int n_base = blockIdx.y*64;
  const bf16_t* Bw = Wt_all + (size_t)layer*NCOLS*Dd;

  floatx4 acc[2][4];
  #pragma unroll
  for (int mi=0;mi<2;mi++)
    #pragma unroll
    for (int ni=0;ni<4;ni++){ floatx4 z = {0.f,0.f,0.f,0.f}; acc[mi][ni] = z; }

  const bf16_t* a0p = A  + (size_t)(m_base + row16)*Dd + quad*8;
  const bf16_t* bp  = Bw + (size_t)(n_base + row16)*Dd + quad*8;
  #pragma unroll
  for (int ks=0; ks<8; ks++){
    bf16x8 a0 = *(const bf16x8*)(a0p + ks*32);
    bf16x8 a1 = *(const bf16x8*)(a0p + 16*Dd + ks*32);
    #pragma unroll
    for (int ni=0;ni<4;ni++){
      bf16x8 b = *(const bf16x8*)(bp + (size_t)ni*16*Dd + ks*32);
      acc[0][ni] = __builtin_amdgcn_mfma_f32_16x16x32_bf16(a0, b, acc[0][ni], 0,0,0);
      acc[1][ni] = __builtin_amdgcn_mfma_f32_16x16x32_bf16(a1, b, acc[1][ni], 0,0,0);
    }
  }

  const int by = blockIdx.y;
  #pragma unroll
  for (int mi=0;mi<2;mi++)
    #pragma unroll
    for (int ni=0;ni<4;ni++){
      int col = n_base + ni*16 + row16;
      #pragma unroll
      for (int r=0;r<4;r++){
        int row = m_base + mi*16 + quad*4 + r;
        float v = acc[mi][ni][r];
        if (by < 4)       vproj_bf[(size_t)row*256 + col]       = (bf16_t)v;
        else if (by < 6)  hsrc_bf[(size_t)row*128 + (col-256)]  = (bf16_t)v;
        else if (by < 8)  hdst_f[(size_t)row*128 + (col-384)]   = v;
        else              qw_bf[(size_t)row*1024 + (col-512)]   = (bf16_t)v;
      }
    }
}

// ---------------- upd GEMM: node = act(node + agg_bf @ Wo) ----------------
__global__ __launch_bounds__(256) void gemm_upd(const bf16_t* __restrict__ A,
    const bf16_t* __restrict__ Wto, float* __restrict__ node, bf16_t* __restrict__ node_bf, int layer){
  const int tid = threadIdx.x;
  const int wave = tid>>6, lane = tid&63;
  const int row16 = lane&15, quad = lane>>4;
  const int m_base = blockIdx.x*128 + wave*32;
  const int n_base = blockIdx.y*64;
  const bf16_t* Bw = Wto + (size_t)layer*Dd*Dd;

  floatx4 acc[2][4];
  #pragma unroll
  for (int mi=0;mi<2;mi++)
    #pragma unroll
    for (int ni=0;ni<4;ni++){ floatx4 z = {0.f,0.f,0.f,0.f}; acc[mi][ni] = z; }

  const bf16_t* a0p = A  + (size_t)(m_base + row16)*Dd + quad*8;
  const bf16_t* bp  = Bw + (size_t)(n_base + row16)*Dd + quad*8;
  #pragma unroll
  for (int ks=0; ks<8; ks++){
    bf16x8 a0 = *(const bf16x8*)(a0p + ks*32);
    bf16x8 a1 = *(const bf16x8*)(a0p + 16*Dd + ks*32);
    #pragma unroll
    for (int ni=0;ni<4;ni++){
      bf16x8 b = *(const bf16x8*)(bp + (size_t)ni*16*Dd + ks*32);
      acc[0][ni] = __builtin_amdgcn_mfma_f32_16x16x32_bf16(a0, b, acc[0][ni], 0,0,0);
      acc[1][ni] = __builtin_amdgcn_mfma_f32_16x16x32_bf16(a1, b, acc[1][ni], 0,0,0);
    }
  }

  #pragma unroll
  for (int mi=0;mi<2;mi++)
    #pragma unroll
    for (int ni=0;ni<4;ni++){
      int col = n_base + ni*16 + row16;
      #pragma unroll
      for (int r=0;r<4;r++){
        int row = m_base + mi*16 + quad*4 + r;
        float v = acc[mi][ni][r] + node[(size_t)row*Dd + col];
        if (col < 64)       v = gelu_fast(v);
        else if (col < 128) v = tanh_fast(v);
        node[(size_t)row*Dd + col] = v;
        node_bf[(size_t)row*Dd + col] = (bf16_t)v;
      }
    }
}

// ---------------- attn: block per node, 3 barriers, register rbf ----------------
__global__ __launch_bounds__(256) void attn_kernel(
    const float* __restrict__ x, const int* __restrict__ src,
    const bf16_t* __restrict__ vproj_bf, const bf16_t* __restrict__ hsrc_bf,
    const float* __restrict__ hdst_f, const bf16_t* __restrict__ qw_bf,
    const float* __restrict__ t_hd, const bf16_t* __restrict__ WrbfT,
    const float* __restrict__ Wvg, const float* __restrict__ Woo,
    bf16_t* __restrict__ agg_bf, float* __restrict__ out, int layer){

  // manual LDS layout, total 11632 B:
  // [0..8704)      s_h   bf16 [32][136]  (hs, then h in place)
  // [8704..9984)   s_sh  f32 [32][10]
  // [9984..10112)  s_cut f32 [32]
  // [10112..10240) s_srcv int [32]
  // [10240..11264) s_logit f32 [32][8]  (logits, then alpha in place)
  // [11264..11584) s_poolsh f32 [8][10]
  // [11584..11632) s_red f32 [4][3]
  __shared__ __align__(16) char smem[11632];
  bf16_t* s_h     = (bf16_t*)(smem);
  float*  s_sh    = (float*)(smem + 8704);
  float*  s_cut   = (float*)(smem + 9984);
  int*    s_srcv  = (int*)  (smem + 10112);
  float*  s_logit = (float*)(smem + 10240);
  float*  s_poolsh= (float*)(smem + 11264);
  float*  s_red   = (float*)(smem + 11584);

  const int tid = threadIdx.x;
  const int bn  = blockIdx.x;
  const int b   = bn >> 10;
  const int wave = tid>>6, lane = tid&63;
  const int row16 = lane&15, quad = lane>>4;

  const float ax = x[(size_t)bn*3+0], ay = x[(size_t)bn*3+1], az = x[(size_t)bn*3+2];

  // P0/P1 merged (NO barrier): issue src + hs gathers early, compute rbf A-frags in regs.
  const int hr = tid>>4;     // hs row pair base (0..15)
  const int hc = tid&15;     // hs col-octet
  const int sH0 = src[(size_t)bn*Kk + hr];
  const int sH1 = src[(size_t)bn*Kk + hr + 16];
  const int sE0 = src[(size_t)bn*Kk + row16];
  const int sE1 = src[(size_t)bn*Kk + row16 + 16];
  bf16x8 hsv0 = *(const bf16x8*)(hsrc_bf + ((size_t)b*Nn + sH0)*128 + hc*8);
  bf16x8 hsv1 = *(const bf16x8*)(hsrc_bf + ((size_t)b*Nn + sH1)*128 + hc*8);

  // per-thread rbf fragment: edges e0=row16, e1=row16+16; basis c = quad*8+j
  bf16x8 a0f, a1f;
  {
    const float* xj0 = x + ((size_t)b*Nn + sE0)*3;
    const float* xj1 = x + ((size_t)b*Nn + sE1)*3;
    float d0x = ax - xj0[0], d0y = ay - xj0[1], d0z = az - xj0[2];
    float d1x = ax - xj1[0], d1y = ay - xj1[1], d1z = az - xj1[2];
    float rr0 = sqrtf(d0x*d0x + d0y*d0y + d0z*d0z);
    float rr1 = sqrtf(d1x*d1x + d1y*d1y + d1z*d1z);
    float xx0 = 10.0f*(1.0f - rr0*0.5f);
    float xx1 = 10.0f*(1.0f - rr1*0.5f);
    float cu0 = (xx0 > 0.0f) ? 1.4f*__expf(-__builtin_amdgcn_rcpf(xx0)) : 0.0f;
    float cu1 = (xx1 > 0.0f) ? 1.4f*__expf(-__builtin_amdgcn_rcpf(xx1)) : 0.0f;
    float sc0 = 4.798224586623f*cu0;
    float sc1 = 4.798224586623f*cu1;
    float rs0 = rr0*15.5f, rs1 = rr1*15.5f;
    float cbase = (float)(quad*8);
    #pragma unroll
    for (int j=0;j<8;j++){
      float c = cbase + (float)j;
      float dd0 = rs0 - c, dd1 = rs1 - c;
      a0f[j] = (bf16_t)(__expf(-dd0*dd0)*sc0);
      a1f[j] = (bf16_t)(__expf(-dd1*dd1)*sc1);
    }
  }

  // lightweight LDS geometry (wave 0 only; consumed after B2/B3)
  if (tid < 32){
    int k = tid;
    int j = src[(size_t)bn*Kk + k];
    s_srcv[k] = j;
    const float* xj = x + ((size_t)b*Nn + j)*3;
    float dx = ax - xj[0], dy = ay - xj[1], dz = az - xj[2];
    float rr = sqrtf(dx*dx + dy*dy + dz*dz);
    float xx = 10.0f*(1.0f - rr*0.5f);
    s_cut[k] = (xx > 0.0f) ? 1.4f*__expf(-__builtin_amdgcn_rcpf(xx)) : 0.0f;
  } else if (tid < 64){
    int k = tid - 32;
    int j = src[(size_t)bn*Kk + k];
    const float* xj = x + ((size_t)b*Nn + j)*3;
    float dx = ax - xj[0], dy = ay - xj[1], dz = az - xj[2];
    float rr = sqrtf(dx*dx + dy*dy + dz*dz);
    float inv = __builtin_amdgcn_rcpf(fmaxf(rr, 1e-9f));
    float ux = dx*inv, uy = dy*inv, uz = dz*inv;
    float* sh = s_sh + k*10;
    sh[0] = 1.0f;
    sh[1] = 1.7320508075688772f*ux;
    sh[2] = 1.7320508075688772f*uy;
    sh[3] = 1.7320508075688772f*uz;
    sh[4] = 3.872983346207417f*ux*uy;
    sh[5] = 3.872983346207417f*uy*uz;
    sh[6] = 1.118033988749895f*(3.0f*uz*uz - 1.0f);
    sh[7] = 3.872983346207417f*ux*uz;
    sh[8] = 1.9364916731037085f*(ux*ux - uy*uy);
  }

  // h-MFMA (rbf regs x WrbfT)
  floatx4 acc[2][2];
  {
    #pragma unroll
    for (int mi=0;mi<2;mi++)
      #pragma unroll
      for (int ni=0;ni<2;ni++){ floatx4 z = {0.f,0.f,0.f,0.f}; acc[mi][ni] = z; }
    const bf16_t* bp = WrbfT + ((size_t)layer*HIDh + wave*32 + row16)*NBnb + quad*8;
    bf16x8 b0 = *(const bf16x8*)(bp);
    bf16x8 b1 = *(const bf16x8*)(bp + 16*NBnb);
    acc[0][0] = __builtin_amdgcn_mfma_f32_16x16x32_bf16(a0f, b0, acc[0][0], 0,0,0);
    acc[0][1] = __builtin_amdgcn_mfma_f32_16x16x32_bf16(a0f, b1, acc[0][1], 0,0,0);
    acc[1][0] = __builtin_amdgcn_mfma_f32_16x16x32_bf16(a1f, b0, acc[1][0], 0,0,0);
    acc[1][1] = __builtin_amdgcn_mfma_f32_16x16x32_bf16(a1f, b1, acc[1][1], 0,0,0);
  }
  // stash hs into s_h
  *(bf16x8*)(s_h + hr*136 + hc*8)        = hsv0;
  *(bf16x8*)(s_h + (hr+16)*136 + hc*8)   = hsv1;
  __syncthreads();   // B2

  // P2: epilogue — h = gelu(acc + hd + hs), IN PLACE in s_h
  #pragma unroll
  for (int ni=0;ni<2;ni++){
    int c = wave*32 + ni*16 + row16;
    float hdv = hdst_f[(size_t)bn*128 + c] + t_hd[(size_t)(layer*Bb + b)*HIDh + c];
    #pragma unroll
    for (int mi=0;mi<2;mi++){
      #pragma unroll
      for (int r=0;r<4;r++){
        int e = mi*16 + quad*4 + r;
        float hs = (float)s_h[e*136 + c];
        s_h[e*136 + c] = (bf16_t)gelu_fast(acc[mi][ni][r] + hdv + hs);
      }
    }
  }
  __syncthreads();   // B3

  // P3: logits MFMA on waves 0,1
  if (wave < 2){
    floatx4 la = {0.f,0.f,0.f,0.f};
    const bf16_t* qp = qw_bf + (size_t)bn*1024 + row16*HIDh + quad*8;
    #pragma unroll
    for (int ks=0; ks<4; ks++){
      bf16x8 a = *(const bf16x8*)(s_h + (wave*16 + row16)*136 + ks*32 + quad*8);
      bf16x8 bq = *(const bf16x8*)(qp + ks*32);
      la = __builtin_amdgcn_mfma_f32_16x16x32_bf16(a, bq, la, 0,0,0);
    }
    if (row16 < Hh){
      #pragma unroll
      for (int r=0;r<4;r++)
        s_logit[(wave*16 + quad*4 + r)*8 + row16] = la[r]*0.17677669529663687f;
    }
  }
  __syncthreads();   // B4

  // P4: softmax + pooling (direct coalesced global gathers) + SH pooling + store / fused out
  {
    const int l = tid & 63;
    const int k = l & 31;
    const int h = tid >> 5;
    float lv = s_logit[k*8 + h];
    float m = lv;
    #pragma unroll
    for (int off=16; off>=1; off>>=1) m = fmaxf(m, __shfl_xor(m, off));
    float w = s_cut[k]*__expf(lv - m);
    float ss = w;
    #pragma unroll
    for (int off=16; off>=1; off>>=1) ss += __shfl_xor(ss, off);
    float alpha = w*__builtin_amdgcn_rcpf(ss + 1e-9f);

    // alpha broadcast via same-wave LDS (in-place over s_logit; write/read by same
    // 32-thread half-wave group => in-order within wave, no barrier)
    s_logit[k*8 + h] = alpha;

    const int sgi = (k < SHDs) ? k : 0;
    float a_m0 = 0.0f, a_m1 = 0.0f, a_sh = 0.0f;
    #pragma unroll
    for (int kk=0; kk<Kk; kk+=2){
      float av0 = s_logit[kk*8 + h];
      float av1 = s_logit[(kk+1)*8 + h];
      a_m0 += av0 * (float)vproj_bf[((size_t)b*Nn + s_srcv[kk])*256 + tid];
      a_m1 += av1 * (float)vproj_bf[((size_t)b*Nn + s_srcv[kk+1])*256 + tid];
      a_sh += av0 * s_sh[kk*10 + sgi] + av1 * s_sh[(kk+1)*10 + sgi];
    }
    float a_main = a_m0 + a_m1;
    if (k < SHDs) s_poolsh[h*10 + k] = a_sh;

    // same-wave LDS write->read (DS ops in-order within a wave)
    const float* wvsh = Wvg + (size_t)layer*265*Dd + 256*Dd;
    #pragma unroll
    for (int sg=0; sg<SHDs; sg++) a_main += s_poolsh[h*10 + sg]*wvsh[sg*Dd + tid];

    if (layer < 3){
      agg_bf[(size_t)bn*Dd + tid] = (bf16_t)a_main;
    } else {
      float p0 = a_main*Woo[tid*3+0];
      float p1 = a_main*Woo[tid*3+1];
      float p2 = a_main*Woo[tid*3+2];
      #pragma unroll
      for (int off=32; off>=1; off>>=1){
        p0 += __shfl_xor(p0, off);
        p1 += __shfl_xor(p1, off);
        p2 += __shfl_xor(p2, off);
      }
      if (lane == 0){ s_red[wave*3+0]=p0; s_red[wave*3+1]=p1; s_red[wave*3+2]=p2; }
      __syncthreads();
      if (tid < 3)
        out[(size_t)bn*3 + tid] = s_red[0*3+tid]+s_red[1*3+tid]+s_red[2*3+tid]+s_red[3*3+tid];
    }
  }
}

extern "C" void kernel_launch(void* const* d_in, const int* in_sizes, int n_in,
                              void* d_out, int out_size, void* d_ws, size_t ws_size,
                              hipStream_t stream){
  const float* x   = (const float*)d_in[0];
  const float* y   = (const float*)d_in[1];
  const float* t   = (const float*)d_in[2];
  const float* We  = (const float*)d_in[3];
  const float* Wk1 = (const float*)d_in[4];
  const float* bk1 = (const float*)d_in[5];
  const float* Wk2 = (const float*)d_in[6];
  const float* Wq  = (const float*)d_in[7];
  const float* Wv  = (const float*)d_in[8];
  const float* Wo  = (const float*)d_in[9];
  const float* Woo = (const float*)d_in[10];
  float* out = (float*)d_out;

  char* ws = (char*)d_ws;
  size_t off = 0;
  auto take = [&](size_t bytes)->char*{ char* p = ws + off; off = (off + bytes + 255) & ~(size_t)255; return p; };

  int*    src      = (int*)   take((size_t)Bb*Nn*Kk*4);
  float*  node     = (float*) take((size_t)Bb*Nn*Dd*4);
  bf16_t* node_bf  = (bf16_t*)take((size_t)Bb*Nn*Dd*2);
  bf16_t* agg_bf   = (bf16_t*)take((size_t)Bb*Nn*Dd*2);
  bf16_t* vproj_bf = (bf16_t*)take((size_t)Bb*Nn*256*2);
  bf16_t* hsrc_bf  = (bf16_t*)take((size_t)Bb*Nn*128*2);
  float*  hdst_f   = (float*) take((size_t)Bb*Nn*128*4);
  bf16_t* qw_bf    = (bf16_t*)take(((size_t)Bb*Nn*1024 + 2048)*2);  // +pad for B-frag overread
  bf16_t* Wt       = (bf16_t*)take((size_t)4*NCOLS*Dd*2);
  bf16_t* Wto      = (bf16_t*)take((size_t)3*Dd*Dd*2);
  bf16_t* WrbfT    = (bf16_t*)take((size_t)4*HIDh*NBnb*2);
  float*  t_hd     = (float*) take((size_t)4*Bb*HIDh*4);

  // weight prep
  wprep_kernel <<<dim3(4,512),  256, 0, stream>>>(Wv, Wk1, Wt);
  wprepM_kernel<<<dim3(4,1024), 256, 0, stream>>>(Wq, Wk2, Wt);
  wprepO_kernel<<<dim3(3,256),  256, 0, stream>>>(Wo, Wto);
  wprepR_kernel<<<dim3(4,128),  32,  0, stream>>>(Wk1, WrbfT);
  tprep_kernel <<<dim3(4,8),    128, 0, stream>>>(t, Wk1, bk1, t_hd);

  knn_kernel  <<<dim3(Bb*Nn/4), 256, 0, stream>>>(x, src);
  embed_kernel<<<dim3(Bb*Nn), 256, 0, stream>>>(y, t, We, node, node_bf);

  for (int l=0; l<4; l++){
    gemm_proj<<<dim3(64,24), 256, 0, stream>>>(node_bf, Wt, vproj_bf, hsrc_bf, hdst_f, qw_bf, l);
    attn_kernel<<<dim3(Bb*Nn), 256, 0, stream>>>(x, src, vproj_bf, hsrc_bf, hdst_f, qw_bf,
                                                 t_hd, WrbfT, Wv, Woo, agg_bf, out, l);
    if (l < 3){
      gemm_upd<<<dim3(64,4), 256, 0, stream>>>(agg_bf, Wto, node, node_bf, l);
    }
  }
}

// Round 13
// 611.636 us; speedup vs baseline: 1.0216x; 1.0024x over previous
//
#include <hip/hip_runtime.h>
#include <math.h>

#define Bb 8
#define Nn 1024
#define Kk 32
#define Dd 256
#define Hh 8
#define DHh 32
#define TDIMt 16
#define NBnb 32
#define HIDh 128
#define NSns 128
#define SHDs 9
#define EINe 304   // NB + TDIM + 2*NS
#define NCOLS 1536 // vproj 256 | hsrc 128 | hdst 128 | qw 1024

typedef __bf16 bf16_t;
typedef bf16_t bf16x8 __attribute__((ext_vector_type(8)));
typedef bf16_t bf16x4 __attribute__((ext_vector_type(4)));
typedef float floatx4 __attribute__((ext_vector_type(4)));

__device__ __forceinline__ float gelu_fast(float x){
  float g = 1.5957691216057308f*(x + 0.044715f*x*x*x);
  return x*__builtin_amdgcn_rcpf(1.0f + __expf(-g));
}
__device__ __forceinline__ float tanh_fast(float x){
  return 1.0f - 2.0f*__builtin_amdgcn_rcpf(1.0f + __expf(2.0f*x));
}

// ---------------- kNN: 256-thread blocks, one wave per node ----------------
__global__ __launch_bounds__(256) void knn_kernel(const float* __restrict__ x, int* __restrict__ src){
  int wave = threadIdx.x >> 6;
  int lane = threadIdx.x & 63;
  int bn = blockIdx.x*4 + wave;
  int b = bn >> 10;
  int n = bn & (Nn-1);
  const float* xb = x + (size_t)b*Nn*3;
  float px = xb[n*3+0], py = xb[n*3+1], pz = xb[n*3+2];
  float d2v[16];
  #pragma unroll
  for (int i=0;i<16;i++){
    int j = i*64 + lane;
    float dx = px - xb[j*3+0];
    float dy = py - xb[j*3+1];
    float dz = pz - xb[j*3+2];
    d2v[i] = dx*dx + dy*dy + dz*dz;
  }
  for (int s=0;s<Kk;s++){
    float best = 3.0e38f; int bslot = 0;
    #pragma unroll
    for (int i=0;i<16;i++){
      if (d2v[i] < best){ best = d2v[i]; bslot = i; }
    }
    int bj = bslot*64 + lane;
    #pragma unroll
    for (int off=32; off>=1; off>>=1){
      float ov = __shfl_xor(best, off);
      int   oj = __shfl_xor(bj,   off);
      if (ov < best || (ov == best && oj < bj)){ best = ov; bj = oj; }
    }
    if ((bj & 63) == lane){
      int sl = bj >> 6;
      #pragma unroll
      for (int i=0;i<16;i++) if (i==sl) d2v[i] = 3.0e38f;
    }
    if (lane == 0) src[(size_t)bn*Kk + s] = bj;
  }
}

// ---------------- embed ----------------
__global__ __launch_bounds__(256) void embed_kernel(const float* __restrict__ y, const float* __restrict__ t,
    const float* __restrict__ We, float* __restrict__ node, bf16_t* __restrict__ node_bf){
  int bn = blockIdx.x; int b = bn >> 10;
  int c = threadIdx.x;
  float f0 = y[(size_t)bn*3+0], f1 = y[(size_t)bn*3+1], f2 = y[(size_t)bn*3+2];
  float a = f0*We[0*Dd+c] + f1*We[1*Dd+c] + f2*We[2*Dd+c];
  #pragma unroll
  for (int i=0;i<TDIMt;i++) a += t[b*TDIMt+i]*We[(3+i)*Dd+c];
  node[(size_t)bn*Dd + c] = a;
  node_bf[(size_t)bn*Dd + c] = (bf16_t)a;
}

// ---------------- weight prep: Wt[l][col][k] bf16, cols 0..511 ----------------
__global__ __launch_bounds__(256) void wprep_kernel(const float* __restrict__ Wv,
    const float* __restrict__ Wk1, bf16_t* __restrict__ Wt){
  int l = blockIdx.x, c = blockIdx.y, k = threadIdx.x;
  const float* wk1l = Wk1 + (size_t)l*EINe*HIDh;
  float v;
  if (c < 256)       v = Wv[(size_t)l*265*Dd + (size_t)k*Dd + c];
  else if (c < 384){ int c2 = c-256; v = (k < 128) ? wk1l[(48+k)*HIDh + c2] : 0.0f; }
  else             { int c2 = c-384; v = (k < 128) ? wk1l[(176+k)*HIDh + c2] : 0.0f; }
  Wt[((size_t)l*NCOLS + c)*Dd + k] = (bf16_t)v;
}

// ---------------- weight prep: fused qw weights M[i][h*128+c] -> cols 512..1535 ----------------
__global__ __launch_bounds__(256) void wprepM_kernel(const float* __restrict__ Wq,
    const float* __restrict__ Wk2, bf16_t* __restrict__ Wt){
  int l = blockIdx.x, y = blockIdx.y, i = threadIdx.x;
  int h = y >> 7, c = y & 127;
  const float* wq  = Wq  + (size_t)l*Dd*Dd   + (size_t)i*Dd + h*DHh;
  const float* wk2 = Wk2 + (size_t)l*HIDh*Dd + (size_t)c*Dd + h*DHh;
  float a = 0.0f;
  #pragma unroll
  for (int d=0; d<DHh; d++) a += wq[d]*wk2[d];
  Wt[((size_t)l*NCOLS + 512 + y)*Dd + i] = (bf16_t)a;
}

// ---------------- weight prep: Wo transposed bf16 ----------------
__global__ __launch_bounds__(256) void wprepO_kernel(const float* __restrict__ Wo, bf16_t* __restrict__ Wto){
  int l = blockIdx.x, c = blockIdx.y, k = threadIdx.x;
  Wto[((size_t)l*Dd + c)*Dd + k] = (bf16_t)Wo[(size_t)l*Dd*Dd + (size_t)k*Dd + c];
}

// ---------------- weight prep: WrbfT[l][c][k] bf16 ----------------
__global__ __launch_bounds__(32) void wprepR_kernel(const float* __restrict__ Wk1, bf16_t* __restrict__ WrbfT){
  int l = blockIdx.x, c = blockIdx.y, k = threadIdx.x;   // k < 32
  WrbfT[((size_t)l*HIDh + c)*NBnb + k] = (bf16_t)Wk1[(size_t)l*EINe*HIDh + (size_t)k*HIDh + c];
}

// ---------------- t_hd[l][b][c] = bk1 + t@Wk1_t ----------------
__global__ __launch_bounds__(128) void tprep_kernel(const float* __restrict__ t,
    const float* __restrict__ Wk1, const float* __restrict__ bk1, float* __restrict__ t_hd){
  int l = blockIdx.x, b = blockIdx.y, c = threadIdx.x;
  const float* wk1l = Wk1 + (size_t)l*EINe*HIDh;
  float a = bk1[l*HIDh + c];
  #pragma unroll
  for (int i=0;i<TDIMt;i++) a += t[b*TDIMt+i]*wk1l[(32+i)*HIDh + c];
  t_hd[(l*Bb + b)*HIDh + c] = a;
}

// ---------------- proj GEMM (layer 0 only) ----------------
__global__ __launch_bounds__(256) void gemm_proj(const bf16_t* __restrict__ A,
    const bf16_t* __restrict__ Wt_all, bf16_t* __restrict__ vproj_bf,
    bf16_t* __restrict__ hsrc_bf, float* __restrict__ hdst_f,
    bf16_t* __restrict__ qw_bf, int layer){
  const int tid = threadIdx.x;
  const int wave = tid>>6, lane = tid&63;
  const int row16 = lane&15, quad = lane>>4;
  const int m_base = blockIdx.x*128 + wave*32;
  const int n_base = blockIdx.y*64;
  const bf16_t* Bw = Wt_all + (size_t)layer*NCOLS*Dd;

  floatx4 acc[2][4];
  #pragma unroll
  for (int mi=0;mi<2;mi++)
    #pragma unroll
    for (int ni=0;ni<4;ni++){ floatx4 z = {0.f,0.f,0.f,0.f}; acc[mi][ni] = z; }

  const bf16_t* a0p = A  + (size_t)(m_base + row16)*Dd + quad*8;
  const bf16_t* bp  = Bw + (size_t)(n_base + row16)*Dd + quad*8;
  #pragma unroll
  for (int ks=0; ks<8; ks++){
    bf16x8 a0 = *(const bf16x8*)(a0p + ks*32);
    bf16x8 a1 = *(const bf16x8*)(a0p + 16*Dd + ks*32);
    #pragma unroll
    for (int ni=0;ni<4;ni++){
      bf16x8 b = *(const bf16x8*)(bp + (size_t)ni*16*Dd + ks*32);
      acc[0][ni] = __builtin_amdgcn_mfma_f32_16x16x32_bf16(a0, b, acc[0][ni], 0,0,0);
      acc[1][ni] = __builtin_amdgcn_mfma_f32_16x16x32_bf16(a1, b, acc[1][ni], 0,0,0);
    }
  }

  const int by = blockIdx.y;
  #pragma unroll
  for (int mi=0;mi<2;mi++)
    #pragma unroll
    for (int ni=0;ni<4;ni++){
      int col = n_base + ni*16 + row16;
      #pragma unroll
      for (int r=0;r<4;r++){
        int row = m_base + mi*16 + quad*4 + r;
        float v = acc[mi][ni][r];
        if (by < 4)       vproj_bf[(size_t)row*256 + col]       = (bf16_t)v;
        else if (by < 6)  hsrc_bf[(size_t)row*128 + (col-256)]  = (bf16_t)v;
        else if (by < 8)  hdst_f[(size_t)row*128 + (col-384)]   = v;
        else              qw_bf[(size_t)row*1024 + (col-512)]   = (bf16_t)v;
      }
    }
}

// ---------------- fused upd(lu) + proj(lp=lu+1): 32 node rows per block ----------------
__global__ __launch_bounds__(256) void gemm_updproj(
    const bf16_t* __restrict__ agg_bf, const bf16_t* __restrict__ Wto,
    float* __restrict__ node, const bf16_t* __restrict__ Wt_all,
    bf16_t* __restrict__ vproj_bf, bf16_t* __restrict__ hsrc_bf,
    float* __restrict__ hdst_f, bf16_t* __restrict__ qw_bf, int lu){

  __shared__ __align__(16) bf16_t s_n[32*264];   // fresh node tile, bf16, padded stride
  const int tid = threadIdx.x;
  const int wave = tid>>6, lane = tid&63;
  const int row16 = lane&15, quad = lane>>4;
  const int m0 = blockIdx.x*32;
  const int lp = lu + 1;

  // ---- Phase U: node[m0..m0+32) = act(node + agg_bf @ Wo[lu]) ----
  {
    const bf16_t* Bw = Wto + (size_t)lu*Dd*Dd;
    floatx4 acc[2][4];
    #pragma unroll
    for (int mi=0;mi<2;mi++)
      #pragma unroll
      for (int ni=0;ni<4;ni++){ floatx4 z = {0.f,0.f,0.f,0.f}; acc[mi][ni] = z; }
    const bf16_t* a0p = agg_bf + (size_t)(m0 + row16)*Dd + quad*8;
    const bf16_t* bp  = Bw + (size_t)(wave*64 + row16)*Dd + quad*8;
    #pragma unroll
    for (int ks=0; ks<8; ks++){
      bf16x8 a0 = *(const bf16x8*)(a0p + ks*32);
      bf16x8 a1 = *(const bf16x8*)(a0p + 16*Dd + ks*32);
      #pragma unroll
      for (int ni=0;ni<4;ni++){
        bf16x8 b = *(const bf16x8*)(bp + (size_t)ni*16*Dd + ks*32);
        acc[0][ni] = __builtin_amdgcn_mfma_f32_16x16x32_bf16(a0, b, acc[0][ni], 0,0,0);
        acc[1][ni] = __builtin_amdgcn_mfma_f32_16x16x32_bf16(a1, b, acc[1][ni], 0,0,0);
      }
    }
    #pragma unroll
    for (int mi=0;mi<2;mi++)
      #pragma unroll
      for (int ni=0;ni<4;ni++){
        int col = wave*64 + ni*16 + row16;
        #pragma unroll
        for (int r=0;r<4;r++){
          int lr  = mi*16 + quad*4 + r;
          int row = m0 + lr;
          float v = acc[mi][ni][r] + node[(size_t)row*Dd + col];
          if (col < 64)       v = gelu_fast(v);
          else if (col < 128) v = tanh_fast(v);
          node[(size_t)row*Dd + col] = v;
          s_n[lr*264 + col] = (bf16_t)v;
        }
      }
  }
  __syncthreads();

  // ---- Phase P: proj(lp) for these 32 rows, A from LDS ----
  #pragma unroll 1
  for (int c=0; c<6; c++){
    const int colbase = c*256 + wave*64;
    floatx4 acc[2][4];
    #pragma unroll
    for (int mi=0;mi<2;mi++)
      #pragma unroll
      for (int ni=0;ni<4;ni++){ floatx4 z = {0.f,0.f,0.f,0.f}; acc[mi][ni] = z; }
    const bf16_t* bp = Wt_all + (size_t)lp*NCOLS*Dd + (size_t)(colbase + row16)*Dd + quad*8;
    #pragma unroll
    for (int ks=0; ks<8; ks++){
      bf16x8 a0 = *(const bf16x8*)&s_n[row16*264 + quad*8 + ks*32];
      bf16x8 a1 = *(const bf16x8*)&s_n[(16+row16)*264 + quad*8 + ks*32];
      #pragma unroll
      for (int ni=0;ni<4;ni++){
        bf16x8 b = *(const bf16x8*)(bp + (size_t)ni*16*Dd + ks*32);
        acc[0][ni] = __builtin_amdgcn_mfma_f32_16x16x32_bf16(a0, b, acc[0][ni], 0,0,0);
        acc[1][ni] = __builtin_amdgcn_mfma_f32_16x16x32_bf16(a1, b, acc[1][ni], 0,0,0);
      }
    }
    #pragma unroll
    for (int mi=0;mi<2;mi++)
      #pragma unroll
      for (int ni=0;ni<4;ni++){
        int col = colbase + ni*16 + row16;
        #pragma unroll
        for (int r=0;r<4;r++){
          int row = m0 + mi*16 + quad*4 + r;
          float v = acc[mi][ni][r];
          if (colbase < 256)      vproj_bf[(size_t)row*256 + col]      = (bf16_t)v;
          else if (colbase < 384) hsrc_bf[(size_t)row*128 + (col-256)] = (bf16_t)v;
          else if (colbase < 512) hdst_f[(size_t)row*128 + (col-384)]  = v;
          else                    qw_bf[(size_t)row*1024 + (col-512)]  = (bf16_t)v;
        }
      }
  }
}

// ---------------- attn: block per node, 3 barriers, register rbf ----------------
__global__ __launch_bounds__(256) void attn_kernel(
    const float* __restrict__ x, const int* __restrict__ src,
    const bf16_t* __restrict__ vproj_bf, const bf16_t* __restrict__ hsrc_bf,
    const float* __restrict__ hdst_f, const bf16_t* __restrict__ qw_bf,
    const float* __restrict__ t_hd, const bf16_t* __restrict__ WrbfT,
    const float* __restrict__ Wvg, const float* __restrict__ Woo,
    bf16_t* __restrict__ agg_bf, float* __restrict__ out, int layer){

  __shared__ __align__(16) char smem[11632];
  bf16_t* s_h     = (bf16_t*)(smem);
  float*  s_sh    = (float*)(smem + 8704);
  float*  s_cut   = (float*)(smem + 9984);
  int*    s_srcv  = (int*)  (smem + 10112);
  float*  s_logit = (float*)(smem + 10240);
  float*  s_poolsh= (float*)(smem + 11264);
  float*  s_red   = (float*)(smem + 11584);

  const int tid = threadIdx.x;
  const int bn  = blockIdx.x;
  const int b   = bn >> 10;
  const int wave = tid>>6, lane = tid&63;
  const int row16 = lane&15, quad = lane>>4;

  const float ax = x[(size_t)bn*3+0], ay = x[(size_t)bn*3+1], az = x[(size_t)bn*3+2];

  const int hr = tid>>4;
  const int hc = tid&15;
  const int sH0 = src[(size_t)bn*Kk + hr];
  const int sH1 = src[(size_t)bn*Kk + hr + 16];
  const int sE0 = src[(size_t)bn*Kk + row16];
  const int sE1 = src[(size_t)bn*Kk + row16 + 16];
  bf16x8 hsv0 = *(const bf16x8*)(hsrc_bf + ((size_t)b*Nn + sH0)*128 + hc*8);
  bf16x8 hsv1 = *(const bf16x8*)(hsrc_bf + ((size_t)b*Nn + sH1)*128 + hc*8);

  bf16x8 a0f, a1f;
  {
    const float* xj0 = x + ((size_t)b*Nn + sE0)*3;
    const float* xj1 = x + ((size_t)b*Nn + sE1)*3;
    float d0x = ax - xj0[0], d0y = ay - xj0[1], d0z = az - xj0[2];
    float d1x = ax - xj1[0], d1y = ay - xj1[1], d1z = az - xj1[2];
    float rr0 = sqrtf(d0x*d0x + d0y*d0y + d0z*d0z);
    float rr1 = sqrtf(d1x*d1x + d1y*d1y + d1z*d1z);
    float xx0 = 10.0f*(1.0f - rr0*0.5f);
    float xx1 = 10.0f*(1.0f - rr1*0.5f);
    float cu0 = (xx0 > 0.0f) ? 1.4f*__expf(-__builtin_amdgcn_rcpf(xx0)) : 0.0f;
    float cu1 = (xx1 > 0.0f) ? 1.4f*__expf(-__builtin_amdgcn_rcpf(xx1)) : 0.0f;
    float sc0 = 4.798224586623f*cu0;
    float sc1 = 4.798224586623f*cu1;
    float rs0 = rr0*15.5f, rs1 = rr1*15.5f;
    float cbase = (float)(quad*8);
    #pragma unroll
    for (int j=0;j<8;j++){
      float c = cbase + (float)j;
      float dd0 = rs0 - c, dd1 = rs1 - c;
      a0f[j] = (bf16_t)(__expf(-dd0*dd0)*sc0);
      a1f[j] = (bf16_t)(__expf(-dd1*dd1)*sc1);
    }
  }

  if (tid < 32){
    int k = tid;
    int j = src[(size_t)bn*Kk + k];
    s_srcv[k] = j;
    const float* xj = x + ((size_t)b*Nn + j)*3;
    float dx = ax - xj[0], dy = ay - xj[1], dz = az - xj[2];
    float rr = sqrtf(dx*dx + dy*dy + dz*dz);
    float xx = 10.0f*(1.0f - rr*0.5f);
    s_cut[k] = (xx > 0.0f) ? 1.4f*__expf(-__builtin_amdgcn_rcpf(xx)) : 0.0f;
  } else if (tid < 64){
    int k = tid - 32;
    int j = src[(size_t)bn*Kk + k];
    const float* xj = x + ((size_t)b*Nn + j)*3;
    float dx = ax - xj[0], dy = ay - xj[1], dz = az - xj[2];
    float rr = sqrtf(dx*dx + dy*dy + dz*dz);
    float inv = __builtin_amdgcn_rcpf(fmaxf(rr, 1e-9f));
    float ux = dx*inv, uy = dy*inv, uz = dz*inv;
    float* sh = s_sh + k*10;
    sh[0] = 1.0f;
    sh[1] = 1.7320508075688772f*ux;
    sh[2] = 1.7320508075688772f*uy;
    sh[3] = 1.7320508075688772f*uz;
    sh[4] = 3.872983346207417f*ux*uy;
    sh[5] = 3.872983346207417f*uy*uz;
    sh[6] = 1.118033988749895f*(3.0f*uz*uz - 1.0f);
    sh[7] = 3.872983346207417f*ux*uz;
    sh[8] = 1.9364916731037085f*(ux*ux - uy*uy);
  }

  floatx4 acc[2][2];
  {
    #pragma unroll
    for (int mi=0;mi<2;mi++)
      #pragma unroll
      for (int ni=0;ni<2;ni++){ floatx4 z = {0.f,0.f,0.f,0.f}; acc[mi][ni] = z; }
    const bf16_t* bp = WrbfT + ((size_t)layer*HIDh + wave*32 + row16)*NBnb + quad*8;
    bf16x8 b0 = *(const bf16x8*)(bp);
    bf16x8 b1 = *(const bf16x8*)(bp + 16*NBnb);
    acc[0][0] = __builtin_amdgcn_mfma_f32_16x16x32_bf16(a0f, b0, acc[0][0], 0,0,0);
    acc[0][1] = __builtin_amdgcn_mfma_f32_16x16x32_bf16(a0f, b1, acc[0][1], 0,0,0);
    acc[1][0] = __builtin_amdgcn_mfma_f32_16x16x32_bf16(a1f, b0, acc[1][0], 0,0,0);
    acc[1][1] = __builtin_amdgcn_mfma_f32_16x16x32_bf16(a1f, b1, acc[1][1], 0,0,0);
  }
  *(bf16x8*)(s_h + hr*136 + hc*8)      = hsv0;
  *(bf16x8*)(s_h + (hr+16)*136 + hc*8) = hsv1;
  __syncthreads();

  #pragma unroll
  for (int ni=0;ni<2;ni++){
    int c = wave*32 + ni*16 + row16;
    float hdv = hdst_f[(size_t)bn*128 + c] + t_hd[(size_t)(layer*Bb + b)*HIDh + c];
    #pragma unroll
    for (int mi=0;mi<2;mi++){
      #pragma unroll
      for (int r=0;r<4;r++){
        int e = mi*16 + quad*4 + r;
        float hs = (float)s_h[e*136 + c];
        s_h[e*136 + c] = (bf16_t)gelu_fast(acc[mi][ni][r] + hdv + hs);
      }
    }
  }
  __syncthreads();

  if (wave < 2){
    floatx4 la = {0.f,0.f,0.f,0.f};
    const bf16_t* qp = qw_bf + (size_t)bn*1024 + row16*HIDh + quad*8;
    #pragma unroll
    for (int ks=0; ks<4; ks++){
      bf16x8 a = *(const bf16x8*)(s_h + (wave*16 + row16)*136 + ks*32 + quad*8);
      bf16x8 bq = *(const bf16x8*)(qp + ks*32);
      la = __builtin_amdgcn_mfma_f32_16x16x32_bf16(a, bq, la, 0,0,0);
    }
    if (row16 < Hh){
      #pragma unroll
      for (int r=0;r<4;r++)
        s_logit[(wave*16 + quad*4 + r)*8 + row16] = la[r]*0.17677669529663687f;
    }
  }
  __syncthreads();

  {
    const int l = tid & 63;
    const int k = l & 31;
    const int h = tid >> 5;
    float lv = s_logit[k*8 + h];
    float m = lv;
    #pragma unroll
    for (int off=16; off>=1; off>>=1) m = fmaxf(m, __shfl_xor(m, off));
    float w = s_cut[k]*__expf(lv - m);
    float ss = w;
    #pragma unroll
    for (int off=16; off>=1; off>>=1) ss += __shfl_xor(ss, off);
    float alpha = w*__builtin_amdgcn_rcpf(ss + 1e-9f);

    s_logit[k*8 + h] = alpha;

    const int sgi = (k < SHDs) ? k : 0;
    float a_m0 = 0.0f, a_m1 = 0.0f, a_sh = 0.0f;
    #pragma unroll
    for (int kk=0; kk<Kk; kk+=2){
      float av0 = s_logit[kk*8 + h];
      float av1 = s_logit[(kk+1)*8 + h];
      a_m0 += av0 * (float)vproj_bf[((size_t)b*Nn + s_srcv[kk])*256 + tid];
      a_m1 += av1 * (float)vproj_bf[((size_t)b*Nn + s_srcv[kk+1])*256 + tid];
      a_sh += av0 * s_sh[kk*10 + sgi] + av1 * s_sh[(kk+1)*10 + sgi];
    }
    float a_main = a_m0 + a_m1;
    if (k < SHDs) s_poolsh[h*10 + k] = a_sh;

    const float* wvsh = Wvg + (size_t)layer*265*Dd + 256*Dd;
    #pragma unroll
    for (int sg=0; sg<SHDs; sg++) a_main += s_poolsh[h*10 + sg]*wvsh[sg*Dd + tid];

    if (layer < 3){
      agg_bf[(size_t)bn*Dd + tid] = (bf16_t)a_main;
    } else {
      float p0 = a_main*Woo[tid*3+0];
      float p1 = a_main*Woo[tid*3+1];
      float p2 = a_main*Woo[tid*3+2];
      #pragma unroll
      for (int off=32; off>=1; off>>=1){
        p0 += __shfl_xor(p0, off);
        p1 += __shfl_xor(p1, off);
        p2 += __shfl_xor(p2, off);
      }
      if (lane == 0){ s_red[wave*3+0]=p0; s_red[wave*3+1]=p1; s_red[wave*3+2]=p2; }
      __syncthreads();
      if (tid < 3)
        out[(size_t)bn*3 + tid] = s_red[0*3+tid]+s_red[1*3+tid]+s_red[2*3+tid]+s_red[3*3+tid];
    }
  }
}

extern "C" void kernel_launch(void* const* d_in, const int* in_sizes, int n_in,
                              void* d_out, int out_size, void* d_ws, size_t ws_size,
                              hipStream_t stream){
  const float* x   = (const float*)d_in[0];
  const float* y   = (const float*)d_in[1];
  const float* t   = (const float*)d_in[2];
  const float* We  = (const float*)d_in[3];
  const float* Wk1 = (const float*)d_in[4];
  const float* bk1 = (const float*)d_in[5];
  const float* Wk2 = (const float*)d_in[6];
  const float* Wq  = (const float*)d_in[7];
  const float* Wv  = (const float*)d_in[8];
  const float* Wo  = (const float*)d_in[9];
  const float* Woo = (const float*)d_in[10];
  float* out = (float*)d_out;

  char* ws = (char*)d_ws;
  size_t off = 0;
  auto take = [&](size_t bytes)->char*{ char* p = ws + off; off = (off + bytes + 255) & ~(size_t)255; return p; };

  int*    src      = (int*)   take((size_t)Bb*Nn*Kk*4);
  float*  node     = (float*) take((size_t)Bb*Nn*Dd*4);
  bf16_t* node_bf  = (bf16_t*)take((size_t)Bb*Nn*Dd*2);
  bf16_t* agg_bf   = (bf16_t*)take((size_t)Bb*Nn*Dd*2);
  bf16_t* vproj_bf = (bf16_t*)take((size_t)Bb*Nn*256*2);
  bf16_t* hsrc_bf  = (bf16_t*)take((size_t)Bb*Nn*128*2);
  float*  hdst_f   = (float*) take((size_t)Bb*Nn*128*4);
  bf16_t* qw_bf    = (bf16_t*)take(((size_t)Bb*Nn*1024 + 2048)*2);  // +pad for B-frag overread
  bf16_t* Wt       = (bf16_t*)take((size_t)4*NCOLS*Dd*2);
  bf16_t* Wto      = (bf16_t*)take((size_t)3*Dd*Dd*2);
  bf16_t* WrbfT    = (bf16_t*)take((size_t)4*HIDh*NBnb*2);
  float*  t_hd     = (float*) take((size_t)4*Bb*HIDh*4);

  // weight prep
  wprep_kernel <<<dim3(4,512),  256, 0, stream>>>(Wv, Wk1, Wt);
  wprepM_kernel<<<dim3(4,1024), 256, 0, stream>>>(Wq, Wk2, Wt);
  wprepO_kernel<<<dim3(3,256),  256, 0, stream>>>(Wo, Wto);
  wprepR_kernel<<<dim3(4,128),  32,  0, stream>>>(Wk1, WrbfT);
  tprep_kernel <<<dim3(4,8),    128, 0, stream>>>(t, Wk1, bk1, t_hd);

  knn_kernel  <<<dim3(Bb*Nn/4), 256, 0, stream>>>(x, src);
  embed_kernel<<<dim3(Bb*Nn), 256, 0, stream>>>(y, t, We, node, node_bf);

  // layer 0 projection from embedded node
  gemm_proj<<<dim3(64,24), 256, 0, stream>>>(node_bf, Wt, vproj_bf, hsrc_bf, hdst_f, qw_bf, 0);
  attn_kernel<<<dim3(Bb*Nn), 256, 0, stream>>>(x, src, vproj_bf, hsrc_bf, hdst_f, qw_bf,
                                               t_hd, WrbfT, Wv, Woo, agg_bf, out, 0);
  for (int l=1; l<4; l++){
    gemm_updproj<<<dim3(Bb*Nn/32), 256, 0, stream>>>(agg_bf, Wto, node, Wt,
                                                     vproj_bf, hsrc_bf, hdst_f, qw_bf, l-1);
    attn_kernel<<<dim3(Bb*Nn), 256, 0, stream>>>(x, src, vproj_bf, hsrc_bf, hdst_f, qw_bf,
                                                 t_hd, WrbfT, Wv, Woo, agg_bf, out, l);
  }
}

// Round 14
// 599.523 us; speedup vs baseline: 1.0422x; 1.0202x over previous
//
#include <hip/hip_runtime.h>
#include <math.h>

#define Bb 8
#define Nn 1024
#define Kk 32
#define Dd 256
#define Hh 8
#define DHh 32
#define TDIMt 16
#define NBnb 32
#define HIDh 128
#define NSns 128
#define SHDs 9
#define EINe 304   // NB + TDIM + 2*NS
#define NCOLS 1536 // vproj 256 | hsrc 128 | hdst 128 | qw 1024

typedef __bf16 bf16_t;
typedef bf16_t bf16x8 __attribute__((ext_vector_type(8)));
typedef float floatx4 __attribute__((ext_vector_type(4)));

__device__ __forceinline__ float gelu_fast(float x){
  float g = 1.5957691216057308f*(x + 0.044715f*x*x*x);
  return x*__builtin_amdgcn_rcpf(1.0f + __expf(-g));
}
__device__ __forceinline__ float tanh_fast(float x){
  return 1.0f - 2.0f*__builtin_amdgcn_rcpf(1.0f + __expf(2.0f*x));
}

// ---------------- setup: all weight preps + knn + embed in ONE dispatch ----------------
// blockIdx.x ranges:
//  [0,2048)      wprep   (Wt cols 0..511)
//  [2048,6144)   wprepM  (Wt cols 512..1535)
//  [6144,6912)   wprepO
//  [6912,6976)   wprepR
//  [6976,6992)   tprep
//  [6992,9040)   knn
//  [9040,17232)  embed
__global__ __launch_bounds__(256) void setup_kernel(
    const float* __restrict__ x, const float* __restrict__ y, const float* __restrict__ t,
    const float* __restrict__ We, const float* __restrict__ Wk1, const float* __restrict__ bk1,
    const float* __restrict__ Wk2, const float* __restrict__ Wq, const float* __restrict__ Wv,
    const float* __restrict__ Wo,
    bf16_t* __restrict__ Wt, bf16_t* __restrict__ Wto, bf16_t* __restrict__ WrbfT,
    float* __restrict__ t_hd, int* __restrict__ src,
    float* __restrict__ node, bf16_t* __restrict__ node_bf){

  const int bid = blockIdx.x, tid = threadIdx.x;

  if (bid < 2048){                       // ---- wprep: Wt[l][c][k], c<512
    int l = bid>>9, c = bid&511, k = tid;
    const float* wk1l = Wk1 + (size_t)l*EINe*HIDh;
    float v;
    if (c < 256)       v = Wv[(size_t)l*265*Dd + (size_t)k*Dd + c];
    else if (c < 384){ int c2 = c-256; v = (k < 128) ? wk1l[(48+k)*HIDh + c2] : 0.0f; }
    else             { int c2 = c-384; v = (k < 128) ? wk1l[(176+k)*HIDh + c2] : 0.0f; }
    Wt[((size_t)l*NCOLS + c)*Dd + k] = (bf16_t)v;
  } else if (bid < 6144){                // ---- wprepM: fused Wq*Wk2 -> Wt cols 512..1535
    int i = bid-2048; int l = i>>10, yy = i&1023;
    int h = yy>>7, c = yy&127; int ii = tid;
    const float* wq  = Wq  + (size_t)l*Dd*Dd   + (size_t)ii*Dd + h*DHh;
    const float* wk2 = Wk2 + (size_t)l*HIDh*Dd + (size_t)c*Dd + h*DHh;
    float a = 0.0f;
    #pragma unroll
    for (int d=0; d<DHh; d++) a += wq[d]*wk2[d];
    Wt[((size_t)l*NCOLS + 512 + yy)*Dd + ii] = (bf16_t)a;
  } else if (bid < 6912){                // ---- wprepO
    int i = bid-6144; int l = i>>8; int c = i&255; int k = tid;
    Wto[((size_t)l*Dd + c)*Dd + k] = (bf16_t)Wo[(size_t)l*Dd*Dd + (size_t)k*Dd + c];
  } else if (bid < 6976){                // ---- wprepR
    int i = bid-6912; int l = i>>4, cg = i&15;
    int c = cg*8 + (tid>>5), k = tid&31;
    WrbfT[((size_t)l*HIDh + c)*NBnb + k] = (bf16_t)Wk1[(size_t)l*EINe*HIDh + (size_t)k*HIDh + c];
  } else if (bid < 6992){                // ---- tprep
    int i = bid-6976; int pair = i*2 + (tid>>7);
    int l = pair>>3, b = pair&7, c = tid&127;
    const float* wk1l = Wk1 + (size_t)l*EINe*HIDh;
    float a = bk1[l*HIDh + c];
    #pragma unroll
    for (int ii=0;ii<TDIMt;ii++) a += t[b*TDIMt+ii]*wk1l[(32+ii)*HIDh + c];
    t_hd[(l*Bb + b)*HIDh + c] = a;
  } else if (bid < 9040){                // ---- knn (one wave per node)
    int wave = tid >> 6, lane = tid & 63;
    int bn = (bid-6992)*4 + wave;
    int b = bn >> 10, n = bn & (Nn-1);
    const float* xb = x + (size_t)b*Nn*3;
    float px = xb[n*3+0], py = xb[n*3+1], pz = xb[n*3+2];
    float d2v[16];
    #pragma unroll
    for (int i=0;i<16;i++){
      int j = i*64 + lane;
      float dx = px - xb[j*3+0];
      float dy = py - xb[j*3+1];
      float dz = pz - xb[j*3+2];
      d2v[i] = dx*dx + dy*dy + dz*dz;
    }
    for (int s=0;s<Kk;s++){
      float best = 3.0e38f; int bslot = 0;
      #pragma unroll
      for (int i=0;i<16;i++){
        if (d2v[i] < best){ best = d2v[i]; bslot = i; }
      }
      int bj = bslot*64 + lane;
      #pragma unroll
      for (int off=32; off>=1; off>>=1){
        float ov = __shfl_xor(best, off);
        int   oj = __shfl_xor(bj,   off);
        if (ov < best || (ov == best && oj < bj)){ best = ov; bj = oj; }
      }
      if ((bj & 63) == lane){
        int sl = bj >> 6;
        #pragma unroll
        for (int i=0;i<16;i++) if (i==sl) d2v[i] = 3.0e38f;
      }
      if (lane == 0) src[(size_t)bn*Kk + s] = bj;
    }
  } else {                               // ---- embed
    int bn = bid-9040; int b = bn >> 10; int c = tid;
    float f0 = y[(size_t)bn*3+0], f1 = y[(size_t)bn*3+1], f2 = y[(size_t)bn*3+2];
    float a = f0*We[0*Dd+c] + f1*We[1*Dd+c] + f2*We[2*Dd+c];
    #pragma unroll
    for (int i=0;i<TDIMt;i++) a += t[b*TDIMt+i]*We[(3+i)*Dd+c];
    node[(size_t)bn*Dd + c] = a;
    node_bf[(size_t)bn*Dd + c] = (bf16_t)a;
  }
}

// ---------------- proj GEMM (layer 0 only); hdst gets +t_hd folded in ----------------
__global__ __launch_bounds__(256) void gemm_proj(const bf16_t* __restrict__ A,
    const bf16_t* __restrict__ Wt_all, float* __restrict__ vproj_f,
    bf16_t* __restrict__ hsrc_bf, float* __restrict__ hdst_f,
    bf16_t* __restrict__ qw_bf, const float* __restrict__ t_hd, int layer){
  const int tid = threadIdx.x;
  const int wave = tid>>6, lane = tid&63;
  const int row16 = lane&15, quad = lane>>4;
  const int m_base = blockIdx.x*128 + wave*32;
  const int n_base = blockIdx.y*64;
  const bf16_t* Bw = Wt_all + (size_t)layer*NCOLS*Dd;

  floatx4 acc[2][4];
  #pragma unroll
  for (int mi=0;mi<2;mi++)
    #pragma unroll
    for (int ni=0;ni<4;ni++){ floatx4 z = {0.f,0.f,0.f,0.f}; acc[mi][ni] = z; }

  const bf16_t* a0p = A  + (size_t)(m_base + row16)*Dd + quad*8;
  const bf16_t* bp  = Bw + (size_t)(n_base + row16)*Dd + quad*8;
  #pragma unroll
  for (int ks=0; ks<8; ks++){
    bf16x8 a0 = *(const bf16x8*)(a0p + ks*32);
    bf16x8 a1 = *(const bf16x8*)(a0p + 16*Dd + ks*32);
    #pragma unroll
    for (int ni=0;ni<4;ni++){
      bf16x8 b = *(const bf16x8*)(bp + (size_t)ni*16*Dd + ks*32);
      acc[0][ni] = __builtin_amdgcn_mfma_f32_16x16x32_bf16(a0, b, acc[0][ni], 0,0,0);
      acc[1][ni] = __builtin_amdgcn_mfma_f32_16x16x32_bf16(a1, b, acc[1][ni], 0,0,0);
    }
  }

  const int by = blockIdx.y;
  const int bb = m_base >> 10;
  #pragma unroll
  for (int mi=0;mi<2;mi++)
    #pragma unroll
    for (int ni=0;ni<4;ni++){
      int col = n_base + ni*16 + row16;
      #pragma unroll
      for (int r=0;r<4;r++){
        int row = m_base + mi*16 + quad*4 + r;
        float v = acc[mi][ni][r];
        if (by < 4)       vproj_f[(size_t)row*256 + col]        = v;
        else if (by < 6)  hsrc_bf[(size_t)row*128 + (col-256)]  = (bf16_t)v;
        else if (by < 8)  hdst_f[(size_t)row*128 + (col-384)]   = v + t_hd[(size_t)(layer*Bb + bb)*HIDh + (col-384)];
        else              qw_bf[(size_t)row*1024 + (col-512)]   = (bf16_t)v;
      }
    }
}

// ---------------- fused upd(lu) + proj(lp=lu+1): 32 node rows per block ----------------
__global__ __launch_bounds__(256) void gemm_updproj(
    const bf16_t* __restrict__ agg_bf, const bf16_t* __restrict__ Wto,
    float* __restrict__ node, const bf16_t* __restrict__ Wt_all,
    float* __restrict__ vproj_f, bf16_t* __restrict__ hsrc_bf,
    float* __restrict__ hdst_f, bf16_t* __restrict__ qw_bf,
    const float* __restrict__ t_hd, int lu){

  __shared__ __align__(16) bf16_t s_n[32*264];
  const int tid = threadIdx.x;
  const int wave = tid>>6, lane = tid&63;
  const int row16 = lane&15, quad = lane>>4;
  const int m0 = blockIdx.x*32;
  const int lp = lu + 1;
  const int bb = m0 >> 10;

  // ---- Phase U ----
  {
    const bf16_t* Bw = Wto + (size_t)lu*Dd*Dd;
    floatx4 acc[2][4];
    #pragma unroll
    for (int mi=0;mi<2;mi++)
      #pragma unroll
      for (int ni=0;ni<4;ni++){ floatx4 z = {0.f,0.f,0.f,0.f}; acc[mi][ni] = z; }
    const bf16_t* a0p = agg_bf + (size_t)(m0 + row16)*Dd + quad*8;
    const bf16_t* bp  = Bw + (size_t)(wave*64 + row16)*Dd + quad*8;
    #pragma unroll
    for (int ks=0; ks<8; ks++){
      bf16x8 a0 = *(const bf16x8*)(a0p + ks*32);
      bf16x8 a1 = *(const bf16x8*)(a0p + 16*Dd + ks*32);
      #pragma unroll
      for (int ni=0;ni<4;ni++){
        bf16x8 b = *(const bf16x8*)(bp + (size_t)ni*16*Dd + ks*32);
        acc[0][ni] = __builtin_amdgcn_mfma_f32_16x16x32_bf16(a0, b, acc[0][ni], 0,0,0);
        acc[1][ni] = __builtin_amdgcn_mfma_f32_16x16x32_bf16(a1, b, acc[1][ni], 0,0,0);
      }
    }
    #pragma unroll
    for (int mi=0;mi<2;mi++)
      #pragma unroll
      for (int ni=0;ni<4;ni++){
        int col = wave*64 + ni*16 + row16;
        #pragma unroll
        for (int r=0;r<4;r++){
          int lr  = mi*16 + quad*4 + r;
          int row = m0 + lr;
          float v = acc[mi][ni][r] + node[(size_t)row*Dd + col];
          if (col < 64)       v = gelu_fast(v);
          else if (col < 128) v = tanh_fast(v);
          node[(size_t)row*Dd + col] = v;
          s_n[lr*264 + col] = (bf16_t)v;
        }
      }
  }
  __syncthreads();

  // ---- Phase P ----
  #pragma unroll 1
  for (int c=0; c<6; c++){
    const int colbase = c*256 + wave*64;
    floatx4 acc[2][4];
    #pragma unroll
    for (int mi=0;mi<2;mi++)
      #pragma unroll
      for (int ni=0;ni<4;ni++){ floatx4 z = {0.f,0.f,0.f,0.f}; acc[mi][ni] = z; }
    const bf16_t* bp = Wt_all + (size_t)lp*NCOLS*Dd + (size_t)(colbase + row16)*Dd + quad*8;
    #pragma unroll
    for (int ks=0; ks<8; ks++){
      bf16x8 a0 = *(const bf16x8*)&s_n[row16*264 + quad*8 + ks*32];
      bf16x8 a1 = *(const bf16x8*)&s_n[(16+row16)*264 + quad*8 + ks*32];
      #pragma unroll
      for (int ni=0;ni<4;ni++){
        bf16x8 b = *(const bf16x8*)(bp + (size_t)ni*16*Dd + ks*32);
        acc[0][ni] = __builtin_amdgcn_mfma_f32_16x16x32_bf16(a0, b, acc[0][ni], 0,0,0);
        acc[1][ni] = __builtin_amdgcn_mfma_f32_16x16x32_bf16(a1, b, acc[1][ni], 0,0,0);
      }
    }
    #pragma unroll
    for (int mi=0;mi<2;mi++)
      #pragma unroll
      for (int ni=0;ni<4;ni++){
        int col = colbase + ni*16 + row16;
        #pragma unroll
        for (int r=0;r<4;r++){
          int row = m0 + mi*16 + quad*4 + r;
          float v = acc[mi][ni][r];
          if (colbase < 256)      vproj_f[(size_t)row*256 + col]       = v;
          else if (colbase < 384) hsrc_bf[(size_t)row*128 + (col-256)] = (bf16_t)v;
          else if (colbase < 512) hdst_f[(size_t)row*128 + (col-384)]  = v + t_hd[(size_t)(lp*Bb + bb)*HIDh + (col-384)];
          else                    qw_bf[(size_t)row*1024 + (col-512)]  = (bf16_t)v;
        }
      }
  }
}

// ---------------- attn: block per node ----------------
__global__ __launch_bounds__(256) void attn_kernel(
    const float* __restrict__ x, const int* __restrict__ src,
    const float* __restrict__ vproj_f, const bf16_t* __restrict__ hsrc_bf,
    const float* __restrict__ hdst_f, const bf16_t* __restrict__ qw_bf,
    const bf16_t* __restrict__ WrbfT,
    const float* __restrict__ Wvg, const float* __restrict__ Woo,
    bf16_t* __restrict__ agg_bf, float* __restrict__ out, int layer){

  __shared__ __align__(16) char smem[11632];
  bf16_t* s_h     = (bf16_t*)(smem);
  float*  s_sh    = (float*)(smem + 8704);
  float*  s_cut   = (float*)(smem + 9984);
  int*    s_srcv  = (int*)  (smem + 10112);
  float*  s_logit = (float*)(smem + 10240);
  float*  s_poolsh= (float*)(smem + 11264);
  float*  s_red   = (float*)(smem + 11584);

  const int tid = threadIdx.x;
  const int bn  = blockIdx.x;
  const int b   = bn >> 10;
  const int wave = tid>>6, lane = tid&63;
  const int row16 = lane&15, quad = lane>>4;

  const float ax = x[(size_t)bn*3+0], ay = x[(size_t)bn*3+1], az = x[(size_t)bn*3+2];

  const int hr = tid>>4;
  const int hc = tid&15;
  const int sH0 = src[(size_t)bn*Kk + hr];
  const int sH1 = src[(size_t)bn*Kk + hr + 16];
  const int sE0 = src[(size_t)bn*Kk + row16];
  const int sE1 = src[(size_t)bn*Kk + row16 + 16];
  bf16x8 hsv0 = *(const bf16x8*)(hsrc_bf + ((size_t)b*Nn + sH0)*128 + hc*8);
  bf16x8 hsv1 = *(const bf16x8*)(hsrc_bf + ((size_t)b*Nn + sH1)*128 + hc*8);

  // rbf A-fragments via Gaussian recurrence: e_{c+1} = e_c * exp(2*dd-1), ratio *= e^-2
  bf16x8 a0f, a1f;
  {
    const float* xj0 = x + ((size_t)b*Nn + sE0)*3;
    const float* xj1 = x + ((size_t)b*Nn + sE1)*3;
    float d0x = ax - xj0[0], d0y = ay - xj0[1], d0z = az - xj0[2];
    float d1x = ax - xj1[0], d1y = ay - xj1[1], d1z = az - xj1[2];
    float rr0 = sqrtf(d0x*d0x + d0y*d0y + d0z*d0z);
    float rr1 = sqrtf(d1x*d1x + d1y*d1y + d1z*d1z);
    float xx0 = 10.0f*(1.0f - rr0*0.5f);
    float xx1 = 10.0f*(1.0f - rr1*0.5f);
    float cu0 = (xx0 > 0.0f) ? 1.4f*__expf(-__builtin_amdgcn_rcpf(xx0)) : 0.0f;
    float cu1 = (xx1 > 0.0f) ? 1.4f*__expf(-__builtin_amdgcn_rcpf(xx1)) : 0.0f;
    float sc0 = 4.798224586623f*cu0;
    float sc1 = 4.798224586623f*cu1;
    // clamp rs: for rs>31 cut==0 so sc==0; clamp keeps exp(2*dd-1) finite
    float rs0 = fminf(rr0*15.5f, 33.0f);
    float rs1 = fminf(rr1*15.5f, 33.0f);
    float cbase = (float)(quad*8);
    float dd0 = rs0 - cbase, dd1 = rs1 - cbase;
    float e0 = __expf(-dd0*dd0)*sc0;
    float e1 = __expf(-dd1*dd1)*sc1;
    float g0 = __expf(2.0f*dd0 - 1.0f);
    float g1 = __expf(2.0f*dd1 - 1.0f);
    a0f[0] = (bf16_t)e0; a1f[0] = (bf16_t)e1;
    #pragma unroll
    for (int j=1;j<8;j++){
      e0 *= g0; e1 *= g1;
      a0f[j] = (bf16_t)e0; a1f[j] = (bf16_t)e1;
      g0 *= 0.13533528323661270f; g1 *= 0.13533528323661270f;
    }
  }

  if (tid < 32){
    int k = tid;
    int j = src[(size_t)bn*Kk + k];
    s_srcv[k] = j;
    const float* xj = x + ((size_t)b*Nn + j)*3;
    float dx = ax - xj[0], dy = ay - xj[1], dz = az - xj[2];
    float rr = sqrtf(dx*dx + dy*dy + dz*dz);
    float xx = 10.0f*(1.0f - rr*0.5f);
    s_cut[k] = (xx > 0.0f) ? 1.4f*__expf(-__builtin_amdgcn_rcpf(xx)) : 0.0f;
  } else if (tid < 64){
    int k = tid - 32;
    int j = src[(size_t)bn*Kk + k];
    const float* xj = x + ((size_t)b*Nn + j)*3;
    float dx = ax - xj[0], dy = ay - xj[1], dz = az - xj[2];
    float rr = sqrtf(dx*dx + dy*dy + dz*dz);
    float inv = __builtin_amdgcn_rcpf(fmaxf(rr, 1e-9f));
    float ux = dx*inv, uy = dy*inv, uz = dz*inv;
    float* sh = s_sh + k*10;
    sh[0] = 1.0f;
    sh[1] = 1.7320508075688772f*ux;
    sh[2] = 1.7320508075688772f*uy;
    sh[3] = 1.7320508075688772f*uz;
    sh[4] = 3.872983346207417f*ux*uy;
    sh[5] = 3.872983346207417f*uy*uz;
    sh[6] = 1.118033988749895f*(3.0f*uz*uz - 1.0f);
    sh[7] = 3.872983346207417f*ux*uz;
    sh[8] = 1.9364916731037085f*(ux*ux - uy*uy);
  }

  floatx4 acc[2][2];
  {
    #pragma unroll
    for (int mi=0;mi<2;mi++)
      #pragma unroll
      for (int ni=0;ni<2;ni++){ floatx4 z = {0.f,0.f,0.f,0.f}; acc[mi][ni] = z; }
    const bf16_t* bp = WrbfT + ((size_t)layer*HIDh + wave*32 + row16)*NBnb + quad*8;
    bf16x8 b0 = *(const bf16x8*)(bp);
    bf16x8 b1 = *(const bf16x8*)(bp + 16*NBnb);
    acc[0][0] = __builtin_amdgcn_mfma_f32_16x16x32_bf16(a0f, b0, acc[0][0], 0,0,0);
    acc[0][1] = __builtin_amdgcn_mfma_f32_16x16x32_bf16(a0f, b1, acc[0][1], 0,0,0);
    acc[1][0] = __builtin_amdgcn_mfma_f32_16x16x32_bf16(a1f, b0, acc[1][0], 0,0,0);
    acc[1][1] = __builtin_amdgcn_mfma_f32_16x16x32_bf16(a1f, b1, acc[1][1], 0,0,0);
  }
  *(bf16x8*)(s_h + hr*136 + hc*8)      = hsv0;
  *(bf16x8*)(s_h + (hr+16)*136 + hc*8) = hsv1;
  __syncthreads();

  // epilogue: h = gelu(acc + hd + hs), in place (hdst_f already includes t_hd)
  #pragma unroll
  for (int ni=0;ni<2;ni++){
    int c = wave*32 + ni*16 + row16;
    float hdv = hdst_f[(size_t)bn*128 + c];
    #pragma unroll
    for (int mi=0;mi<2;mi++){
      #pragma unroll
      for (int r=0;r<4;r++){
        int e = mi*16 + quad*4 + r;
        float hs = (float)s_h[e*136 + c];
        s_h[e*136 + c] = (bf16_t)gelu_fast(acc[mi][ni][r] + hdv + hs);
      }
    }
  }
  __syncthreads();

  if (wave < 2){
    floatx4 la = {0.f,0.f,0.f,0.f};
    const bf16_t* qp = qw_bf + (size_t)bn*1024 + row16*HIDh + quad*8;
    #pragma unroll
    for (int ks=0; ks<4; ks++){
      bf16x8 a = *(const bf16x8*)(s_h + (wave*16 + row16)*136 + ks*32 + quad*8);
      bf16x8 bq = *(const bf16x8*)(qp + ks*32);
      la = __builtin_amdgcn_mfma_f32_16x16x32_bf16(a, bq, la, 0,0,0);
    }
    if (row16 < Hh){
      #pragma unroll
      for (int r=0;r<4;r++)
        s_logit[(wave*16 + quad*4 + r)*8 + row16] = la[r]*0.17677669529663687f;
    }
  }
  __syncthreads();

  {
    const int l = tid & 63;
    const int k = l & 31;
    const int h = tid >> 5;
    float lv = s_logit[k*8 + h];
    float m = lv;
    #pragma unroll
    for (int off=16; off>=1; off>>=1) m = fmaxf(m, __shfl_xor(m, off));
    float w = s_cut[k]*__expf(lv - m);
    float ss = w;
    #pragma unroll
    for (int off=16; off>=1; off>>=1) ss += __shfl_xor(ss, off);
    float alpha = w*__builtin_amdgcn_rcpf(ss + 1e-9f);

    s_logit[k*8 + h] = alpha;   // same half-wave group re-reads below: in-order within wave

    const int sgi = (k < SHDs) ? k : 0;
    float a_m0 = 0.0f, a_m1 = 0.0f, a_sh = 0.0f;
    #pragma unroll
    for (int kk=0; kk<Kk; kk+=2){
      float av0 = s_logit[kk*8 + h];
      float av1 = s_logit[(kk+1)*8 + h];
      a_m0 += av0 * vproj_f[((size_t)b*Nn + s_srcv[kk])*256 + tid];
      a_m1 += av1 * vproj_f[((size_t)b*Nn + s_srcv[kk+1])*256 + tid];
      a_sh += av0 * s_sh[kk*10 + sgi] + av1 * s_sh[(kk+1)*10 + sgi];
    }
    float a_main = a_m0 + a_m1;
    if (k < SHDs) s_poolsh[h*10 + k] = a_sh;

    const float* wvsh = Wvg + (size_t)layer*265*Dd + 256*Dd;
    #pragma unroll
    for (int sg=0; sg<SHDs; sg++) a_main += s_poolsh[h*10 + sg]*wvsh[sg*Dd + tid];

    if (layer < 3){
      agg_bf[(size_t)bn*Dd + tid] = (bf16_t)a_main;
    } else {
      float p0 = a_main*Woo[tid*3+0];
      float p1 = a_main*Woo[tid*3+1];
      float p2 = a_main*Woo[tid*3+2];
      #pragma unroll
      for (int off=32; off>=1; off>>=1){
        p0 += __shfl_xor(p0, off);
        p1 += __shfl_xor(p1, off);
        p2 += __shfl_xor(p2, off);
      }
      if (lane == 0){ s_red[wave*3+0]=p0; s_red[wave*3+1]=p1; s_red[wave*3+2]=p2; }
      __syncthreads();
      if (tid < 3)
        out[(size_t)bn*3 + tid] = s_red[0*3+tid]+s_red[1*3+tid]+s_red[2*3+tid]+s_red[3*3+tid];
    }
  }
}

extern "C" void kernel_launch(void* const* d_in, const int* in_sizes, int n_in,
                              void* d_out, int out_size, void* d_ws, size_t ws_size,
                              hipStream_t stream){
  const float* x   = (const float*)d_in[0];
  const float* y   = (const float*)d_in[1];
  const float* t   = (const float*)d_in[2];
  const float* We  = (const float*)d_in[3];
  const float* Wk1 = (const float*)d_in[4];
  const float* bk1 = (const float*)d_in[5];
  const float* Wk2 = (const float*)d_in[6];
  const float* Wq  = (const float*)d_in[7];
  const float* Wv  = (const float*)d_in[8];
  const float* Wo  = (const float*)d_in[9];
  const float* Woo = (const float*)d_in[10];
  float* out = (float*)d_out;

  char* ws = (char*)d_ws;
  size_t off = 0;
  auto take = [&](size_t bytes)->char*{ char* p = ws + off; off = (off + bytes + 255) & ~(size_t)255; return p; };

  int*    src      = (int*)   take((size_t)Bb*Nn*Kk*4);
  float*  node     = (float*) take((size_t)Bb*Nn*Dd*4);
  bf16_t* node_bf  = (bf16_t*)take((size_t)Bb*Nn*Dd*2);
  bf16_t* agg_bf   = (bf16_t*)take((size_t)Bb*Nn*Dd*2);
  float*  vproj_f  = (float*) take((size_t)Bb*Nn*256*4);
  bf16_t* hsrc_bf  = (bf16_t*)take((size_t)Bb*Nn*128*2);
  float*  hdst_f   = (float*) take((size_t)Bb*Nn*128*4);
  bf16_t* qw_bf    = (bf16_t*)take(((size_t)Bb*Nn*1024 + 2048)*2);  // +pad for B-frag overread
  bf16_t* Wt       = (bf16_t*)take((size_t)4*NCOLS*Dd*2);
  bf16_t* Wto      = (bf16_t*)take((size_t)3*Dd*Dd*2);
  bf16_t* WrbfT    = (bf16_t*)take((size_t)4*HIDh*NBnb*2);
  float*  t_hd     = (float*) take((size_t)4*Bb*HIDh*4);

  setup_kernel<<<dim3(17232), 256, 0, stream>>>(x, y, t, We, Wk1, bk1, Wk2, Wq, Wv, Wo,
                                                Wt, Wto, WrbfT, t_hd, src, node, node_bf);

  gemm_proj<<<dim3(64,24), 256, 0, stream>>>(node_bf, Wt, vproj_f, hsrc_bf, hdst_f, qw_bf, t_hd, 0);
  attn_kernel<<<dim3(Bb*Nn), 256, 0, stream>>>(x, src, vproj_f, hsrc_bf, hdst_f, qw_bf,
                                               WrbfT, Wv, Woo, agg_bf, out, 0);
  for (int l=1; l<4; l++){
    gemm_updproj<<<dim3(Bb*Nn/32), 256, 0, stream>>>(agg_bf, Wto, node, Wt,
                                                     vproj_f, hsrc_bf, hdst_f, qw_bf, t_hd, l-1);
    attn_kernel<<<dim3(Bb*Nn), 256, 0, stream>>>(x, src, vproj_f, hsrc_bf, hdst_f, qw_bf,
                                                 WrbfT, Wv, Woo, agg_bf, out, l);
  }
}

// Round 15
// 582.173 us; speedup vs baseline: 1.0733x; 1.0298x over previous
//
#include <hip/hip_runtime.h>
#include <math.h>

#define Bb 8
#define Nn 1024
#define Kk 32
#define Dd 256
#define Hh 8
#define DHh 32
#define TDIMt 16
#define NBnb 32
#define HIDh 128
#define NSns 128
#define SHDs 9
#define EINe 304   // NB + TDIM + 2*NS
#define NCOLS 1536 // vproj 256 | hsrc 128 | hdst 128 | qw 1024

typedef __bf16 bf16_t;
typedef bf16_t bf16x8 __attribute__((ext_vector_type(8)));
typedef float floatx4 __attribute__((ext_vector_type(4)));

__device__ __forceinline__ float gelu_fast(float x){
  float g = 1.5957691216057308f*(x + 0.044715f*x*x*x);
  return x*__builtin_amdgcn_rcpf(1.0f + __expf(-g));
}
__device__ __forceinline__ float tanh_fast(float x){
  return 1.0f - 2.0f*__builtin_amdgcn_rcpf(1.0f + __expf(2.0f*x));
}

// ---------------- setup: knn FIRST, then preps, then embed ----------------
// blockIdx.x ranges:
//  [0,2048)      knn (4 nodes/block — longest pole, starts at t=0)
//  [2048,6144)   wprepM  (coalesced + shuffle-reduce)
//  [6144,8192)   wprep   (Wt cols 0..511)
//  [8192,8960)   wprepO
//  [8960,9024)   wprepR
//  [9024,9040)   tprep
//  [9040,11088)  embed (4 nodes/block)
__global__ __launch_bounds__(256) void setup_kernel(
    const float* __restrict__ x, const float* __restrict__ y, const float* __restrict__ t,
    const float* __restrict__ We, const float* __restrict__ Wk1, const float* __restrict__ bk1,
    const float* __restrict__ Wk2, const float* __restrict__ Wq, const float* __restrict__ Wv,
    const float* __restrict__ Wo,
    bf16_t* __restrict__ Wt, bf16_t* __restrict__ Wto, bf16_t* __restrict__ WrbfT,
    float* __restrict__ t_hd, int* __restrict__ src,
    float* __restrict__ node, bf16_t* __restrict__ node_bf){

  __shared__ float s_b[32];
  const int bid = blockIdx.x, tid = threadIdx.x;

  if (bid < 2048){                       // ---- knn (one wave per node)
    int wave = tid >> 6, lane = tid & 63;
    int bn = bid*4 + wave;
    int b = bn >> 10, n = bn & (Nn-1);
    const float* xb = x + (size_t)b*Nn*3;
    float px = xb[n*3+0], py = xb[n*3+1], pz = xb[n*3+2];
    float d2v[16];
    #pragma unroll
    for (int i=0;i<16;i++){
      int j = i*64 + lane;
      float dx = px - xb[j*3+0];
      float dy = py - xb[j*3+1];
      float dz = pz - xb[j*3+2];
      d2v[i] = dx*dx + dy*dy + dz*dz;
    }
    for (int s=0;s<Kk;s++){
      float best = 3.0e38f; int bslot = 0;
      #pragma unroll
      for (int i=0;i<16;i++){
        if (d2v[i] < best){ best = d2v[i]; bslot = i; }
      }
      int bj = bslot*64 + lane;
      #pragma unroll
      for (int off=32; off>=1; off>>=1){
        float ov = __shfl_xor(best, off);
        int   oj = __shfl_xor(bj,   off);
        if (ov < best || (ov == best && oj < bj)){ best = ov; bj = oj; }
      }
      if ((bj & 63) == lane){
        int sl = bj >> 6;
        #pragma unroll
        for (int i=0;i<16;i++) if (i==sl) d2v[i] = 3.0e38f;
      }
      if (lane == 0) src[(size_t)bn*Kk + s] = bj;
    }
  } else if (bid < 6144){                // ---- wprepM (coalesced)
    int i = bid-2048; int l = i>>10, yy = i&1023;
    int h = yy>>7, c = yy&127;
    if (tid < 32) s_b[tid] = Wk2[(size_t)l*HIDh*Dd + (size_t)c*Dd + h*DHh + tid];
    __syncthreads();
    const int rloc = tid>>3, dg = tid&7;
    const float b0 = s_b[dg*4+0], b1 = s_b[dg*4+1], b2 = s_b[dg*4+2], b3 = s_b[dg*4+3];
    #pragma unroll
    for (int p=0;p<8;p++){
      int ii = p*32 + rloc;
      const float4 v = *(const float4*)(Wq + (size_t)l*Dd*Dd + (size_t)ii*Dd + h*DHh + dg*4);
      float part = v.x*b0 + v.y*b1 + v.z*b2 + v.w*b3;
      part += __shfl_xor(part, 1);
      part += __shfl_xor(part, 2);
      part += __shfl_xor(part, 4);
      if (dg == 0) Wt[((size_t)l*NCOLS + 512 + yy)*Dd + ii] = (bf16_t)part;
    }
  } else if (bid < 8192){                // ---- wprep: Wt[l][c][k], c<512
    int i = bid-6144; int l = i>>9, c = i&511, k = tid;
    const float* wk1l = Wk1 + (size_t)l*EINe*HIDh;
    float v;
    if (c < 256)       v = Wv[(size_t)l*265*Dd + (size_t)k*Dd + c];
    else if (c < 384){ int c2 = c-256; v = (k < 128) ? wk1l[(48+k)*HIDh + c2] : 0.0f; }
    else             { int c2 = c-384; v = (k < 128) ? wk1l[(176+k)*HIDh + c2] : 0.0f; }
    Wt[((size_t)l*NCOLS + c)*Dd + k] = (bf16_t)v;
  } else if (bid < 8960){                // ---- wprepO
    int i = bid-8192; int l = i>>8; int c = i&255; int k = tid;
    Wto[((size_t)l*Dd + c)*Dd + k] = (bf16_t)Wo[(size_t)l*Dd*Dd + (size_t)k*Dd + c];
  } else if (bid < 9024){                // ---- wprepR
    int i = bid-8960; int l = i>>4, cg = i&15;
    int c = cg*8 + (tid>>5), k = tid&31;
    WrbfT[((size_t)l*HIDh + c)*NBnb + k] = (bf16_t)Wk1[(size_t)l*EINe*HIDh + (size_t)k*HIDh + c];
  } else if (bid < 9040){                // ---- tprep
    int i = bid-9024; int pair = i*2 + (tid>>7);
    int l = pair>>3, b = pair&7, c = tid&127;
    const float* wk1l = Wk1 + (size_t)l*EINe*HIDh;
    float a = bk1[l*HIDh + c];
    #pragma unroll
    for (int ii=0;ii<TDIMt;ii++) a += t[b*TDIMt+ii]*wk1l[(32+ii)*HIDh + c];
    t_hd[(l*Bb + b)*HIDh + c] = a;
  } else {                               // ---- embed (4 nodes/block)
    int bn0 = (bid-9040)*4; int c = tid;
    float w0 = We[0*Dd+c], w1 = We[1*Dd+c], w2 = We[2*Dd+c];
    float wt[TDIMt];
    #pragma unroll
    for (int i=0;i<TDIMt;i++) wt[i] = We[(3+i)*Dd+c];
    #pragma unroll
    for (int u=0;u<4;u++){
      int bn = bn0 + u; int b = bn >> 10;
      float a = y[(size_t)bn*3+0]*w0 + y[(size_t)bn*3+1]*w1 + y[(size_t)bn*3+2]*w2;
      #pragma unroll
      for (int i=0;i<TDIMt;i++) a += t[b*TDIMt+i]*wt[i];
      node[(size_t)bn*Dd + c] = a;
      node_bf[(size_t)bn*Dd + c] = (bf16_t)a;
    }
  }
}

// ---------------- proj GEMM (layer 0 only); hdst gets +t_hd folded in ----------------
__global__ __launch_bounds__(256) void gemm_proj(const bf16_t* __restrict__ A,
    const bf16_t* __restrict__ Wt_all, float* __restrict__ vproj_f,
    bf16_t* __restrict__ hsrc_bf, float* __restrict__ hdst_f,
    bf16_t* __restrict__ qw_bf, const float* __restrict__ t_hd, int layer){
  const int tid = threadIdx.x;
  const int wave = tid>>6, lane = tid&63;
  const int row16 = lane&15, quad = lane>>4;
  const int m_base = blockIdx.x*128 + wave*32;
  const int n_base = blockIdx.y*64;
  const bf16_t* Bw = Wt_all + (size_t)layer*NCOLS*Dd;

  floatx4 acc[2][4];
  #pragma unroll
  for (int mi=0;mi<2;mi++)
    #pragma unroll
    for (int ni=0;ni<4;ni++){ floatx4 z = {0.f,0.f,0.f,0.f}; acc[mi][ni] = z; }

  const bf16_t* a0p = A  + (size_t)(m_base + row16)*Dd + quad*8;
  const bf16_t* bp  = Bw + (size_t)(n_base + row16)*Dd + quad*8;
  #pragma unroll
  for (int ks=0; ks<8; ks++){
    bf16x8 a0 = *(const bf16x8*)(a0p + ks*32);
    bf16x8 a1 = *(const bf16x8*)(a0p + 16*Dd + ks*32);
    #pragma unroll
    for (int ni=0;ni<4;ni++){
      bf16x8 b = *(const bf16x8*)(bp + (size_t)ni*16*Dd + ks*32);
      acc[0][ni] = __builtin_amdgcn_mfma_f32_16x16x32_bf16(a0, b, acc[0][ni], 0,0,0);
      acc[1][ni] = __builtin_amdgcn_mfma_f32_16x16x32_bf16(a1, b, acc[1][ni], 0,0,0);
    }
  }

  const int by = blockIdx.y;
  const int bb = m_base >> 10;
  #pragma unroll
  for (int mi=0;mi<2;mi++)
    #pragma unroll
    for (int ni=0;ni<4;ni++){
      int col = n_base + ni*16 + row16;
      #pragma unroll
      for (int r=0;r<4;r++){
        int row = m_base + mi*16 + quad*4 + r;
        float v = acc[mi][ni][r];
        if (by < 4)       vproj_f[(size_t)row*256 + col]        = v;
        else if (by < 6)  hsrc_bf[(size_t)row*128 + (col-256)]  = (bf16_t)v;
        else if (by < 8)  hdst_f[(size_t)row*128 + (col-384)]   = v + t_hd[(size_t)(layer*Bb + bb)*HIDh + (col-384)];
        else              qw_bf[(size_t)row*1024 + (col-512)]   = (bf16_t)v;
      }
    }
}

// ---------------- fused upd(lu) + proj(lp=lu+1): 32 node rows per block ----------------
__global__ __launch_bounds__(256) void gemm_updproj(
    const bf16_t* __restrict__ agg_bf, const bf16_t* __restrict__ Wto,
    float* __restrict__ node, const bf16_t* __restrict__ Wt_all,
    float* __restrict__ vproj_f, bf16_t* __restrict__ hsrc_bf,
    float* __restrict__ hdst_f, bf16_t* __restrict__ qw_bf,
    const float* __restrict__ t_hd, int lu){

  __shared__ __align__(16) bf16_t s_n[32*264];
  const int tid = threadIdx.x;
  const int wave = tid>>6, lane = tid&63;
  const int row16 = lane&15, quad = lane>>4;
  const int m0 = blockIdx.x*32;
  const int lp = lu + 1;
  const int bb = m0 >> 10;

  // ---- Phase U ----
  {
    const bf16_t* Bw = Wto + (size_t)lu*Dd*Dd;
    floatx4 acc[2][4];
    #pragma unroll
    for (int mi=0;mi<2;mi++)
      #pragma unroll
      for (int ni=0;ni<4;ni++){ floatx4 z = {0.f,0.f,0.f,0.f}; acc[mi][ni] = z; }
    const bf16_t* a0p = agg_bf + (size_t)(m0 + row16)*Dd + quad*8;
    const bf16_t* bp  = Bw + (size_t)(wave*64 + row16)*Dd + quad*8;
    #pragma unroll
    for (int ks=0; ks<8; ks++){
      bf16x8 a0 = *(const bf16x8*)(a0p + ks*32);
      bf16x8 a1 = *(const bf16x8*)(a0p + 16*Dd + ks*32);
      #pragma unroll
      for (int ni=0;ni<4;ni++){
        bf16x8 b = *(const bf16x8*)(bp + (size_t)ni*16*Dd + ks*32);
        acc[0][ni] = __builtin_amdgcn_mfma_f32_16x16x32_bf16(a0, b, acc[0][ni], 0,0,0);
        acc[1][ni] = __builtin_amdgcn_mfma_f32_16x16x32_bf16(a1, b, acc[1][ni], 0,0,0);
      }
    }
    #pragma unroll
    for (int mi=0;mi<2;mi++)
      #pragma unroll
      for (int ni=0;ni<4;ni++){
        int col = wave*64 + ni*16 + row16;
        #pragma unroll
        for (int r=0;r<4;r++){
          int lr  = mi*16 + quad*4 + r;
          int row = m0 + lr;
          float v = acc[mi][ni][r] + node[(size_t)row*Dd + col];
          if (col < 64)       v = gelu_fast(v);
          else if (col < 128) v = tanh_fast(v);
          node[(size_t)row*Dd + col] = v;
          s_n[lr*264 + col] = (bf16_t)v;
        }
      }
  }
  __syncthreads();

  // ---- Phase P ----
  #pragma unroll 1
  for (int c=0; c<6; c++){
    const int colbase = c*256 + wave*64;
    floatx4 acc[2][4];
    #pragma unroll
    for (int mi=0;mi<2;mi++)
      #pragma unroll
      for (int ni=0;ni<4;ni++){ floatx4 z = {0.f,0.f,0.f,0.f}; acc[mi][ni] = z; }
    const bf16_t* bp = Wt_all + (size_t)lp*NCOLS*Dd + (size_t)(colbase + row16)*Dd + quad*8;
    #pragma unroll
    for (int ks=0; ks<8; ks++){
      bf16x8 a0 = *(const bf16x8*)&s_n[row16*264 + quad*8 + ks*32];
      bf16x8 a1 = *(const bf16x8*)&s_n[(16+row16)*264 + quad*8 + ks*32];
      #pragma unroll
      for (int ni=0;ni<4;ni++){
        bf16x8 b = *(const bf16x8*)(bp + (size_t)ni*16*Dd + ks*32);
        acc[0][ni] = __builtin_amdgcn_mfma_f32_16x16x32_bf16(a0, b, acc[0][ni], 0,0,0);
        acc[1][ni] = __builtin_amdgcn_mfma_f32_16x16x32_bf16(a1, b, acc[1][ni], 0,0,0);
      }
    }
    #pragma unroll
    for (int mi=0;mi<2;mi++)
      #pragma unroll
      for (int ni=0;ni<4;ni++){
        int col = colbase + ni*16 + row16;
        #pragma unroll
        for (int r=0;r<4;r++){
          int row = m0 + mi*16 + quad*4 + r;
          float v = acc[mi][ni][r];
          if (colbase < 256)      vproj_f[(size_t)row*256 + col]       = v;
          else if (colbase < 384) hsrc_bf[(size_t)row*128 + (col-256)] = (bf16_t)v;
          else if (colbase < 512) hdst_f[(size_t)row*128 + (col-384)]  = v + t_hd[(size_t)(lp*Bb + bb)*HIDh + (col-384)];
          else                    qw_bf[(size_t)row*1024 + (col-512)]  = (bf16_t)v;
        }
      }
  }
}

// ---------------- attn: block per node ----------------
__global__ __launch_bounds__(256) void attn_kernel(
    const float* __restrict__ x, const int* __restrict__ src,
    const float* __restrict__ vproj_f, const bf16_t* __restrict__ hsrc_bf,
    const float* __restrict__ hdst_f, const bf16_t* __restrict__ qw_bf,
    const bf16_t* __restrict__ WrbfT,
    const float* __restrict__ Wvg, const float* __restrict__ Woo,
    bf16_t* __restrict__ agg_bf, float* __restrict__ out, int layer){

  __shared__ __align__(16) char smem[11632];
  bf16_t* s_h     = (bf16_t*)(smem);
  float*  s_sh    = (float*)(smem + 8704);
  float*  s_cut   = (float*)(smem + 9984);
  int*    s_srcv  = (int*)  (smem + 10112);
  float*  s_logit = (float*)(smem + 10240);
  float*  s_poolsh= (float*)(smem + 11264);
  float*  s_red   = (float*)(smem + 11584);

  const int tid = threadIdx.x;
  const int bn  = blockIdx.x;
  const int b   = bn >> 10;
  const int wave = tid>>6, lane = tid&63;
  const int row16 = lane&15, quad = lane>>4;

  const float ax = x[(size_t)bn*3+0], ay = x[(size_t)bn*3+1], az = x[(size_t)bn*3+2];

  const int hr = tid>>4;
  const int hc = tid&15;
  const int sH0 = src[(size_t)bn*Kk + hr];
  const int sH1 = src[(size_t)bn*Kk + hr + 16];
  const int sE0 = src[(size_t)bn*Kk + row16];
  const int sE1 = src[(size_t)bn*Kk + row16 + 16];
  bf16x8 hsv0 = *(const bf16x8*)(hsrc_bf + ((size_t)b*Nn + sH0)*128 + hc*8);
  bf16x8 hsv1 = *(const bf16x8*)(hsrc_bf + ((size_t)b*Nn + sH1)*128 + hc*8);

  // rbf A-fragments via Gaussian recurrence
  bf16x8 a0f, a1f;
  {
    const float* xj0 = x + ((size_t)b*Nn + sE0)*3;
    const float* xj1 = x + ((size_t)b*Nn + sE1)*3;
    float d0x = ax - xj0[0], d0y = ay - xj0[1], d0z = az - xj0[2];
    float d1x = ax - xj1[0], d1y = ay - xj1[1], d1z = az - xj1[2];
    float rr0 = sqrtf(d0x*d0x + d0y*d0y + d0z*d0z);
    float rr1 = sqrtf(d1x*d1x + d1y*d1y + d1z*d1z);
    float xx0 = 10.0f*(1.0f - rr0*0.5f);
    float xx1 = 10.0f*(1.0f - rr1*0.5f);
    float cu0 = (xx0 > 0.0f) ? 1.4f*__expf(-__builtin_amdgcn_rcpf(xx0)) : 0.0f;
    float cu1 = (xx1 > 0.0f) ? 1.4f*__expf(-__builtin_amdgcn_rcpf(xx1)) : 0.0f;
    float sc0 = 4.798224586623f*cu0;
    float sc1 = 4.798224586623f*cu1;
    float rs0 = fminf(rr0*15.5f, 33.0f);
    float rs1 = fminf(rr1*15.5f, 33.0f);
    float cbase = (float)(quad*8);
    float dd0 = rs0 - cbase, dd1 = rs1 - cbase;
    float e0 = __expf(-dd0*dd0)*sc0;
    float e1 = __expf(-dd1*dd1)*sc1;
    float g0 = __expf(2.0f*dd0 - 1.0f);
    float g1 = __expf(2.0f*dd1 - 1.0f);
    a0f[0] = (bf16_t)e0; a1f[0] = (bf16_t)e1;
    #pragma unroll
    for (int j=1;j<8;j++){
      e0 *= g0; e1 *= g1;
      a0f[j] = (bf16_t)e0; a1f[j] = (bf16_t)e1;
      g0 *= 0.13533528323661270f; g1 *= 0.13533528323661270f;
    }
  }

  if (tid < 32){
    int k = tid;
    int j = src[(size_t)bn*Kk + k];
    s_srcv[k] = j;
    const float* xj = x + ((size_t)b*Nn + j)*3;
    float dx = ax - xj[0], dy = ay - xj[1], dz = az - xj[2];
    float rr = sqrtf(dx*dx + dy*dy + dz*dz);
    float xx = 10.0f*(1.0f - rr*0.5f);
    s_cut[k] = (xx > 0.0f) ? 1.4f*__expf(-__builtin_amdgcn_rcpf(xx)) : 0.0f;
  } else if (tid < 64){
    int k = tid - 32;
    int j = src[(size_t)bn*Kk + k];
    const float* xj = x + ((size_t)b*Nn + j)*3;
    float dx = ax - xj[0], dy = ay - xj[1], dz = az - xj[2];
    float rr = sqrtf(dx*dx + dy*dy + dz*dz);
    float inv = __builtin_amdgcn_rcpf(fmaxf(rr, 1e-9f));
    float ux = dx*inv, uy = dy*inv, uz = dz*inv;
    float* sh = s_sh + k*10;
    sh[0] = 1.0f;
    sh[1] = 1.7320508075688772f*ux;
    sh[2] = 1.7320508075688772f*uy;
    sh[3] = 1.7320508075688772f*uz;
    sh[4] = 3.872983346207417f*ux*uy;
    sh[5] = 3.872983346207417f*uy*uz;
    sh[6] = 1.118033988749895f*(3.0f*uz*uz - 1.0f);
    sh[7] = 3.872983346207417f*ux*uz;
    sh[8] = 1.9364916731037085f*(ux*ux - uy*uy);
  }

  floatx4 acc[2][2];
  {
    #pragma unroll
    for (int mi=0;mi<2;mi++)
      #pragma unroll
      for (int ni=0;ni<2;ni++){ floatx4 z = {0.f,0.f,0.f,0.f}; acc[mi][ni] = z; }
    const bf16_t* bp = WrbfT + ((size_t)layer*HIDh + wave*32 + row16)*NBnb + quad*8;
    bf16x8 b0 = *(const bf16x8*)(bp);
    bf16x8 b1 = *(const bf16x8*)(bp + 16*NBnb);
    acc[0][0] = __builtin_amdgcn_mfma_f32_16x16x32_bf16(a0f, b0, acc[0][0], 0,0,0);
    acc[0][1] = __builtin_amdgcn_mfma_f32_16x16x32_bf16(a0f, b1, acc[0][1], 0,0,0);
    acc[1][0] = __builtin_amdgcn_mfma_f32_16x16x32_bf16(a1f, b0, acc[1][0], 0,0,0);
    acc[1][1] = __builtin_amdgcn_mfma_f32_16x16x32_bf16(a1f, b1, acc[1][1], 0,0,0);
  }
  *(bf16x8*)(s_h + hr*136 + hc*8)      = hsv0;
  *(bf16x8*)(s_h + (hr+16)*136 + hc*8) = hsv1;
  __syncthreads();

  #pragma unroll
  for (int ni=0;ni<2;ni++){
    int c = wave*32 + ni*16 + row16;
    float hdv = hdst_f[(size_t)bn*128 + c];
    #pragma unroll
    for (int mi=0;mi<2;mi++){
      #pragma unroll
      for (int r=0;r<4;r++){
        int e = mi*16 + quad*4 + r;
        float hs = (float)s_h[e*136 + c];
        s_h[e*136 + c] = (bf16_t)gelu_fast(acc[mi][ni][r] + hdv + hs);
      }
    }
  }
  __syncthreads();

  if (wave < 2){
    floatx4 la = {0.f,0.f,0.f,0.f};
    const bf16_t* qp = qw_bf + (size_t)bn*1024 + row16*HIDh + quad*8;
    #pragma unroll
    for (int ks=0; ks<4; ks++){
      bf16x8 a = *(const bf16x8*)(s_h + (wave*16 + row16)*136 + ks*32 + quad*8);
      bf16x8 bq = *(const bf16x8*)(qp + ks*32);
      la = __builtin_amdgcn_mfma_f32_16x16x32_bf16(a, bq, la, 0,0,0);
    }
    if (row16 < Hh){
      #pragma unroll
      for (int r=0;r<4;r++)
        s_logit[(wave*16 + quad*4 + r)*8 + row16] = la[r]*0.17677669529663687f;
    }
  }
  __syncthreads();

  {
    const int l = tid & 63;
    const int k = l & 31;
    const int h = tid >> 5;
    float lv = s_logit[k*8 + h];
    float m = lv;
    #pragma unroll
    for (int off=16; off>=1; off>>=1) m = fmaxf(m, __shfl_xor(m, off));
    float w = s_cut[k]*__expf(lv - m);
    float ss = w;
    #pragma unroll
    for (int off=16; off>=1; off>>=1) ss += __shfl_xor(ss, off);
    float alpha = w*__builtin_amdgcn_rcpf(ss + 1e-9f);

    s_logit[k*8 + h] = alpha;   // same half-wave group re-reads below: in-order within wave

    const int sgi = (k < SHDs) ? k : 0;
    float a_m0 = 0.0f, a_m1 = 0.0f, a_sh = 0.0f;
    #pragma unroll
    for (int kk=0; kk<Kk; kk+=2){
      float av0 = s_logit[kk*8 + h];
      float av1 = s_logit[(kk+1)*8 + h];
      a_m0 += av0 * vproj_f[((size_t)b*Nn + s_srcv[kk])*256 + tid];
      a_m1 += av1 * vproj_f[((size_t)b*Nn + s_srcv[kk+1])*256 + tid];
      a_sh += av0 * s_sh[kk*10 + sgi] + av1 * s_sh[(kk+1)*10 + sgi];
    }
    float a_main = a_m0 + a_m1;
    if (k < SHDs) s_poolsh[h*10 + k] = a_sh;

    const float* wvsh = Wvg + (size_t)layer*265*Dd + 256*Dd;
    #pragma unroll
    for (int sg=0; sg<SHDs; sg++) a_main += s_poolsh[h*10 + sg]*wvsh[sg*Dd + tid];

    if (layer < 3){
      agg_bf[(size_t)bn*Dd + tid] = (bf16_t)a_main;
    } else {
      float p0 = a_main*Woo[tid*3+0];
      float p1 = a_main*Woo[tid*3+1];
      float p2 = a_main*Woo[tid*3+2];
      #pragma unroll
      for (int off=32; off>=1; off>>=1){
        p0 += __shfl_xor(p0, off);
        p1 += __shfl_xor(p1, off);
        p2 += __shfl_xor(p2, off);
      }
      if (lane == 0){ s_red[wave*3+0]=p0; s_red[wave*3+1]=p1; s_red[wave*3+2]=p2; }
      __syncthreads();
      if (tid < 3)
        out[(size_t)bn*3 + tid] = s_red[0*3+tid]+s_red[1*3+tid]+s_red[2*3+tid]+s_red[3*3+tid];
    }
  }
}

extern "C" void kernel_launch(void* const* d_in, const int* in_sizes, int n_in,
                              void* d_out, int out_size, void* d_ws, size_t ws_size,
                              hipStream_t stream){
  const float* x   = (const float*)d_in[0];
  const float* y   = (const float*)d_in[1];
  const float* t   = (const float*)d_in[2];
  const float* We  = (const float*)d_in[3];
  const float* Wk1 = (const float*)d_in[4];
  const float* bk1 = (const float*)d_in[5];
  const float* Wk2 = (const float*)d_in[6];
  const float* Wq  = (const float*)d_in[7];
  const float* Wv  = (const float*)d_in[8];
  const float* Wo  = (const float*)d_in[9];
  const float* Woo = (const float*)d_in[10];
  float* out = (float*)d_out;

  char* ws = (char*)d_ws;
  size_t off = 0;
  auto take = [&](size_t bytes)->char*{ char* p = ws + off; off = (off + bytes + 255) & ~(size_t)255; return p; };

  int*    src      = (int*)   take((size_t)Bb*Nn*Kk*4);
  float*  node     = (float*) take((size_t)Bb*Nn*Dd*4);
  bf16_t* node_bf  = (bf16_t*)take((size_t)Bb*Nn*Dd*2);
  bf16_t* agg_bf   = (bf16_t*)take((size_t)Bb*Nn*Dd*2);
  float*  vproj_f  = (float*) take((size_t)Bb*Nn*256*4);
  bf16_t* hsrc_bf  = (bf16_t*)take((size_t)Bb*Nn*128*2);
  float*  hdst_f   = (float*) take((size_t)Bb*Nn*128*4);
  bf16_t* qw_bf    = (bf16_t*)take(((size_t)Bb*Nn*1024 + 2048)*2);  // +pad for B-frag overread
  bf16_t* Wt       = (bf16_t*)take((size_t)4*NCOLS*Dd*2);
  bf16_t* Wto      = (bf16_t*)take((size_t)3*Dd*Dd*2);
  bf16_t* WrbfT    = (bf16_t*)take((size_t)4*HIDh*NBnb*2);
  float*  t_hd     = (float*) take((size_t)4*Bb*HIDh*4);

  setup_kernel<<<dim3(11088), 256, 0, stream>>>(x, y, t, We, Wk1, bk1, Wk2, Wq, Wv, Wo,
                                                Wt, Wto, WrbfT, t_hd, src, node, node_bf);

  gemm_proj<<<dim3(64,24), 256, 0, stream>>>(node_bf, Wt, vproj_f, hsrc_bf, hdst_f, qw_bf, t_hd, 0);
  attn_kernel<<<dim3(Bb*Nn), 256, 0, stream>>>(x, src, vproj_f, hsrc_bf, hdst_f, qw_bf,
                                               WrbfT, Wv, Woo, agg_bf, out, 0);
  for (int l=1; l<4; l++){
    gemm_updproj<<<dim3(Bb*Nn/32), 256, 0, stream>>>(agg_bf, Wto, node, Wt,
                                                     vproj_f, hsrc_bf, hdst_f, qw_bf, t_hd, l-1);
    attn_kernel<<<dim3(Bb*Nn), 256, 0, stream>>>(x, src, vproj_f, hsrc_bf, hdst_f, qw_bf,
                                                 WrbfT, Wv, Woo, agg_bf, out, l);
  }
}